// Round 5
// baseline (400.010 us; speedup 1.0000x reference)
//
#include <hip/hip_runtime.h>
#include <hip/hip_bf16.h>

static constexpr int BATCH = 1 << 20;
static constexpr size_t ILV_BYTES = (size_t)512 * 512 * 16 * 4;  // 16 MiB

using f32x16 = __attribute__((ext_vector_type(16))) float;
using s16x8  = __attribute__((ext_vector_type(8))) short;
using u32x4  = __attribute__((ext_vector_type(4))) unsigned int;

__device__ __forceinline__ unsigned pkbf(float lo, float hi) {
  unsigned short a = __builtin_bit_cast(unsigned short, __float2bfloat16(lo));
  unsigned short b = __builtin_bit_cast(unsigned short, __float2bfloat16(hi));
  return (unsigned)a | ((unsigned)b << 16);
}

__device__ __forceinline__ u32x4 pack8(const float* __restrict__ p) {
  u32x4 r = {pkbf(p[0], p[1]), pkbf(p[2], p[3]), pkbf(p[4], p[5]), pkbf(p[6], p[7])};
  return r;
}

__device__ __forceinline__ f32x16 mfma_bf16(u32x4 a, u32x4 b, f32x16 c) {
  return __builtin_amdgcn_mfma_f32_32x32x16_bf16(
      __builtin_bit_cast(s16x8, a), __builtin_bit_cast(s16x8, b), c, 0, 0, 0);
}

// D(f32x16) -> leaky -> bf16 B-frags for next layer (K=32).
__device__ __forceinline__ void act_pack_swap(f32x16 acc, u32x4& B0, u32x4& B1) {
  float r[16];
#pragma unroll
  for (int i = 0; i < 16; ++i) {
    float t = acc[i];
    r[i] = fmaxf(t, 0.01f * t);
  }
  unsigned pk[4][2];
#pragma unroll
  for (int b = 0; b < 4; ++b) {
    pk[b][0] = pkbf(r[4 * b + 0], r[4 * b + 1]);
    pk[b][1] = pkbf(r[4 * b + 2], r[4 * b + 3]);
  }
  auto r0 = __builtin_amdgcn_permlane32_swap(pk[0][0], pk[1][0], false, false);
  auto r1 = __builtin_amdgcn_permlane32_swap(pk[0][1], pk[1][1], false, false);
  auto r2 = __builtin_amdgcn_permlane32_swap(pk[2][0], pk[3][0], false, false);
  auto r3 = __builtin_amdgcn_permlane32_swap(pk[2][1], pk[3][1], false, false);
  B0[0] = r0[0]; B0[1] = r1[0]; B0[2] = r0[1]; B0[3] = r1[1];
  B1[0] = r2[0]; B1[1] = r3[0]; B1[2] = r2[1]; B1[3] = r3[1];
}

__device__ __forceinline__ f32x16 load_bias(const float* __restrict__ bp, int h) {
  f32x16 c;
#pragma unroll
  for (int b = 0; b < 4; ++b) {
    float4 t = *reinterpret_cast<const float4*>(bp + 8 * b + 4 * h);
    c[4 * b + 0] = t.x; c[4 * b + 1] = t.y; c[4 * b + 2] = t.z; c[4 * b + 3] = t.w;
  }
  return c;
}

// 4 channels (h: ch4h..4h+3) of bilinear-wrap sample. which: 0=offset,1=rgb.
// ILV: tex is the 16-ch interleaved texture (64B/texel); else the raw 8-ch one.
template <bool ILV>
__device__ __forceinline__ float4 bilin4(const float* __restrict__ tex, float ux,
                                         float uy, int h, int which) {
  float px = ux * 512.0f - 0.5f;
  float py = uy * 512.0f - 0.5f;
  float fpx = floorf(px), fpy = floorf(py);
  float fx = px - fpx, fy = py - fpy;
  int ix = (int)fpx, iy = (int)fpy;
  int x0 = ix & 511, x1 = (ix + 1) & 511;
  int y0 = iy & 511, y1 = (iy + 1) & 511;
  constexpr int SH = ILV ? 4 : 3;
  const int co = (ILV ? (which << 3) : 0) + (h << 2);
  const float* p00 = tex + (((size_t)((y0 << 9) | x0) << SH) + co);
  const float* p01 = tex + (((size_t)((y0 << 9) | x1) << SH) + co);
  const float* p10 = tex + (((size_t)((y1 << 9) | x0) << SH) + co);
  const float* p11 = tex + (((size_t)((y1 << 9) | x1) << SH) + co);
  float4 a = *reinterpret_cast<const float4*>(p00);
  float4 b = *reinterpret_cast<const float4*>(p01);
  float4 c = *reinterpret_cast<const float4*>(p10);
  float4 d = *reinterpret_cast<const float4*>(p11);
  float gx = 1.0f - fx, gy = 1.0f - fy;
  float w00 = gx * gy, w01 = fx * gy, w10 = gx * fy, w11 = fx * fy;
  float4 o;
  o.x = fmaf(d.x, w11, fmaf(c.x, w10, fmaf(b.x, w01, a.x * w00)));
  o.y = fmaf(d.y, w11, fmaf(c.y, w10, fmaf(b.y, w01, a.y * w00)));
  o.z = fmaf(d.z, w11, fmaf(c.z, w10, fmaf(b.z, w01, a.z * w00)));
  o.w = fmaf(d.w, w11, fmaf(c.w, w10, fmaf(b.w, w01, a.w * w00)));
  return o;
}

// Build interleaved texture: ws[texel][0:8]=offset ch, ws[texel][8:16]=rgb ch.
__global__ void __launch_bounds__(256) tex_interleave(
    const float* __restrict__ t0, const float* __restrict__ t1,
    float* __restrict__ ws) {
  int i = blockIdx.x * 256 + threadIdx.x;  // one float4 slot each; 1M slots
  int texel = i >> 2;
  int q = i & 3;
  const float* src = (q < 2 ? t0 : t1) + (((size_t)texel << 3) + ((q & 1) << 2));
  reinterpret_cast<float4*>(ws)[i] = *reinterpret_cast<const float4*>(src);
}

template <bool ILV>
__global__ void __launch_bounds__(256, 5) neumip_mfma(
    const float* __restrict__ cam_g, const float* __restrict__ light_g,
    const float* __restrict__ uv_g, const float* __restrict__ offset_tex,
    const float* __restrict__ rgb_tex, const float* __restrict__ wtex,
    const float* __restrict__ ow0, const float* __restrict__ ob0,
    const float* __restrict__ ow1, const float* __restrict__ ob1,
    const float* __restrict__ ow2, const float* __restrict__ ob2,
    const float* __restrict__ ow3, const float* __restrict__ ob3,
    const float* __restrict__ rw0, const float* __restrict__ rb0,
    const float* __restrict__ rw1, const float* __restrict__ rb1,
    const float* __restrict__ rw2, const float* __restrict__ rb2,
    const float* __restrict__ rw3, const float* __restrict__ rb3,
    float* __restrict__ out) {
  const int tid = threadIdx.x;
  const int lane = tid & 63;
  const int widx = tid >> 6;
  const int h = lane >> 5;
  const int sl = lane & 31;
  const int m = sl;
  const float* texO = ILV ? wtex : offset_tex;
  const float* texR = ILV ? wtex : rgb_tex;

  // Shuffle-based output redistribution constants (lane-invariant across loop).
  // out index j (0..95) = 3*s + c -> value o_c of sample-lane s.
  const int s1 = lane / 3, c1 = lane - 3 * s1;       // for og[lane]
  const int j2 = 64 + sl;
  const int s2 = j2 / 3, c2 = j2 - 3 * s2;           // for og[64+sl]

  // ---------------- weight preload (bf16 A-frags) ----------------
  u32x4 A_o1;
  if (h == 0) {
    A_o1 = pack8(ow0 + 10 * m);
  } else {
    const float* p = ow0 + 10 * m + 8;
    A_o1 = u32x4{pkbf(p[0], p[1]), 0u, 0u, 0u};
  }
  u32x4 A_o2a = pack8(ow1 + 32 * m + 8 * h);
  u32x4 A_o2b = pack8(ow1 + 32 * m + 16 + 8 * h);
  u32x4 A_o3a = pack8(ow2 + 32 * m + 8 * h);
  u32x4 A_o3b = pack8(ow2 + 32 * m + 16 + 8 * h);

  f32x16 w3f;
#pragma unroll
  for (int b = 0; b < 4; ++b) {
    float4 t = *reinterpret_cast<const float4*>(ow3 + 8 * b + 4 * h);
    w3f[4 * b + 0] = t.x; w3f[4 * b + 1] = t.y;
    w3f[4 * b + 2] = t.z; w3f[4 * b + 3] = t.w;
  }

  u32x4 A_r1;
  if (h == 0) {
    A_r1 = pack8(rw0 + 12 * m);
  } else {
    const float* p = rw0 + 12 * m + 8;
    A_r1 = u32x4{pkbf(p[0], p[1]), pkbf(p[2], p[3]), 0u, 0u};
  }
  u32x4 A_r2a = pack8(rw1 + 32 * m + 8 * h);
  u32x4 A_r2b = pack8(rw1 + 32 * m + 16 + 8 * h);
  u32x4 A_r3a = pack8(rw2 + 32 * m + 8 * h);
  u32x4 A_r3b = pack8(rw2 + 32 * m + 16 + 8 * h);
  u32x4 A_r4a, A_r4b;
  if (m < 3) {
    A_r4a = pack8(rw3 + 32 * m + 8 * h);
    A_r4b = pack8(rw3 + 32 * m + 16 + 8 * h);
  } else {
    A_r4a = u32x4{0u, 0u, 0u, 0u};
    A_r4b = u32x4{0u, 0u, 0u, 0u};
  }
  const float b30 = rb3[0], b31 = rb3[1], b32 = rb3[2];
  const float ob3s = ob3[0];

  // ---------------- grid-stride over 32-sample groups ----------------
  const int NG = BATCH / 32;
  const int nw = (int)(gridDim.x * (blockDim.x >> 6));
  int g = (int)blockIdx.x * (int)(blockDim.x >> 6) + widx;
#pragma unroll 1
  for (; g < NG; g += nw) {
    const int S = g * 32 + sl;
    float2 uvv = reinterpret_cast<const float2*>(uv_g)[S];
    float2 cam = reinterpret_cast<const float2*>(cam_g)[S];
    float2 light = reinterpret_cast<const float2*>(light_g)[S];

    // ---- offset-branch input B-frag ----
    float4 ch = bilin4<ILV>(texO, uvv.x, uvv.y, h, 0);
    unsigned V0 = pkbf(ch.x, ch.y), V1 = pkbf(ch.z, ch.w);
    auto t0 = __builtin_amdgcn_permlane32_swap(V0, V0, false, false);
    auto t1 = __builtin_amdgcn_permlane32_swap(V1, V1, false, false);
    unsigned camk = pkbf(cam.x, cam.y);
    u32x4 Bin;
    Bin[0] = h ? camk : V0;
    Bin[1] = h ? 0u : V1;
    Bin[2] = h ? 0u : t0[1];
    Bin[3] = h ? 0u : t1[1];

    // ---- offset MLP ----
    f32x16 acc = load_bias(ob0, h);
    acc = mfma_bf16(A_o1, Bin, acc);
    u32x4 B0, B1;
    act_pack_swap(acc, B0, B1);
    acc = load_bias(ob1, h);
    acc = mfma_bf16(A_o2a, B0, acc);
    acc = mfma_bf16(A_o2b, B1, acc);
    act_pack_swap(acc, B0, B1);
    acc = load_bias(ob2, h);
    acc = mfma_bf16(A_o3a, B0, acc);
    acc = mfma_bf16(A_o3b, B1, acc);

    float part = 0.0f;
#pragma unroll
    for (int i = 0; i < 16; ++i) {
      float t = acc[i];
      t = fmaxf(t, 0.01f * t);
      part = fmaf(w3f[i], t, part);
    }
    float depth = part + __shfl_xor(part, 32) + ob3s;

    // ---- displacement ----
    float s2f = fmaf(cam.x, cam.x, cam.y * cam.y);
    float z = sqrtf(fmaxf(1.0f - s2f, 1e-6f));
    float drz = depth * (1.0f / z);
    float u2x = fmaf(cam.x, drz, uvv.x);
    float u2y = fmaf(cam.y, drz, uvv.y);

    // ---- rgb-branch input B-frag ----
    float4 chr = bilin4<ILV>(texR, u2x, u2y, h, 1);
    unsigned P0 = pkbf(chr.x, chr.y), P1 = pkbf(chr.z, chr.w);
    u32x4 Brin;
    Brin[0] = h ? P0 : pkbf(light.x, light.y);
    Brin[1] = h ? P1 : camk;
    Brin[2] = h ? 0u : P0;
    Brin[3] = h ? 0u : P1;

    // ---- rgb MLP ----
    acc = load_bias(rb0, h);
    acc = mfma_bf16(A_r1, Brin, acc);
    act_pack_swap(acc, B0, B1);
    acc = load_bias(rb1, h);
    acc = mfma_bf16(A_r2a, B0, acc);
    acc = mfma_bf16(A_r2b, B1, acc);
    act_pack_swap(acc, B0, B1);
    acc = load_bias(rb2, h);
    acc = mfma_bf16(A_r3a, B0, acc);
    acc = mfma_bf16(A_r3b, B1, acc);
    act_pack_swap(acc, B0, B1);
    f32x16 accf;
#pragma unroll
    for (int i = 0; i < 16; ++i) accf[i] = 0.0f;
    accf = mfma_bf16(A_r4a, B0, accf);
    accf = mfma_bf16(A_r4b, B1, accf);

    // ---- shuffle-packed coalesced store (race-free, no LDS) ----
    // o0..o2 valid in h=0 lanes (sample sl); all shfl sources are < 32.
    float o0 = accf[0] + b30, o1 = accf[1] + b31, o2 = accf[2] + b32;
    float a0 = __shfl(o0, s1), a1 = __shfl(o1, s1), a2 = __shfl(o2, s1);
    float v1 = (c1 == 0) ? a0 : ((c1 == 1) ? a1 : a2);
    float d0 = __shfl(o0, s2), d1 = __shfl(o1, s2), d2 = __shfl(o2, s2);
    float v2 = (c2 == 0) ? d0 : ((c2 == 1) ? d1 : d2);
    float* og = out + (size_t)g * 96;
    og[lane] = v1;
    if (h == 1) og[64 + sl] = v2;
  }
}

extern "C" void kernel_launch(void* const* d_in, const int* in_sizes, int n_in,
                              void* d_out, int out_size, void* d_ws, size_t ws_size,
                              hipStream_t stream) {
  const float* cam = (const float*)d_in[0];
  const float* light = (const float*)d_in[1];
  const float* uv = (const float*)d_in[2];
  const float* offset_tex = (const float*)d_in[3];
  const float* rgb_tex = (const float*)d_in[4];
  const float* ow0 = (const float*)d_in[5];
  const float* ob0 = (const float*)d_in[6];
  const float* ow1 = (const float*)d_in[7];
  const float* ob1 = (const float*)d_in[8];
  const float* ow2 = (const float*)d_in[9];
  const float* ob2 = (const float*)d_in[10];
  const float* ow3 = (const float*)d_in[11];
  const float* ob3 = (const float*)d_in[12];
  const float* rw0 = (const float*)d_in[13];
  const float* rb0 = (const float*)d_in[14];
  const float* rw1 = (const float*)d_in[15];
  const float* rb1 = (const float*)d_in[16];
  const float* rw2 = (const float*)d_in[17];
  const float* rb2 = (const float*)d_in[18];
  const float* rw3 = (const float*)d_in[19];
  const float* rb3 = (const float*)d_in[20];
  float* out = (float*)d_out;
  float* wtex = (float*)d_ws;

  dim3 block(256);
  if (ws_size >= ILV_BYTES) {
    hipLaunchKernelGGL(tex_interleave, dim3(4096), block, 0, stream, offset_tex,
                       rgb_tex, wtex);
    hipLaunchKernelGGL(neumip_mfma<true>, dim3(2048), block, 0, stream, cam,
                       light, uv, offset_tex, rgb_tex, wtex, ow0, ob0, ow1, ob1,
                       ow2, ob2, ow3, ob3, rw0, rb0, rw1, rb1, rw2, rb2, rw3,
                       rb3, out);
  } else {
    hipLaunchKernelGGL(neumip_mfma<false>, dim3(2048), block, 0, stream, cam,
                       light, uv, offset_tex, rgb_tex, wtex, ow0, ob0, ow1, ob1,
                       ow2, ob2, ow3, ob3, rw0, rb0, rw1, rb1, rw2, rb2, rw3,
                       rb3, out);
  }
}

// Round 6
// 341.476 us; speedup vs baseline: 1.1714x; 1.1714x over previous
//
#include <hip/hip_runtime.h>
#include <hip/hip_bf16.h>

static constexpr int BATCH = 1 << 20;

using f32x16 = __attribute__((ext_vector_type(16))) float;
using s16x8  = __attribute__((ext_vector_type(8))) short;
using u32x4  = __attribute__((ext_vector_type(4))) unsigned int;

__device__ __forceinline__ unsigned pkbf(float lo, float hi) {
  unsigned short a = __builtin_bit_cast(unsigned short, __float2bfloat16(lo));
  unsigned short b = __builtin_bit_cast(unsigned short, __float2bfloat16(hi));
  return (unsigned)a | ((unsigned)b << 16);
}

__device__ __forceinline__ u32x4 pack8(const float* __restrict__ p) {
  u32x4 r = {pkbf(p[0], p[1]), pkbf(p[2], p[3]), pkbf(p[4], p[5]), pkbf(p[6], p[7])};
  return r;
}

__device__ __forceinline__ f32x16 mfma_bf16(u32x4 a, u32x4 b, f32x16 c) {
  return __builtin_amdgcn_mfma_f32_32x32x16_bf16(
      __builtin_bit_cast(s16x8, a), __builtin_bit_cast(s16x8, b), c, 0, 0, 0);
}

// D(f32x16) -> leaky -> bf16 B-frags for next layer (K=32).
__device__ __forceinline__ void act_pack_swap(f32x16 acc, u32x4& B0, u32x4& B1) {
  float r[16];
#pragma unroll
  for (int i = 0; i < 16; ++i) {
    float t = acc[i];
    r[i] = fmaxf(t, 0.01f * t);
  }
  unsigned pk[4][2];
#pragma unroll
  for (int b = 0; b < 4; ++b) {
    pk[b][0] = pkbf(r[4 * b + 0], r[4 * b + 1]);
    pk[b][1] = pkbf(r[4 * b + 2], r[4 * b + 3]);
  }
  auto r0 = __builtin_amdgcn_permlane32_swap(pk[0][0], pk[1][0], false, false);
  auto r1 = __builtin_amdgcn_permlane32_swap(pk[0][1], pk[1][1], false, false);
  auto r2 = __builtin_amdgcn_permlane32_swap(pk[2][0], pk[3][0], false, false);
  auto r3 = __builtin_amdgcn_permlane32_swap(pk[2][1], pk[3][1], false, false);
  B0[0] = r0[0]; B0[1] = r1[0]; B0[2] = r0[1]; B0[3] = r1[1];
  B1[0] = r2[0]; B1[1] = r3[0]; B1[2] = r2[1]; B1[3] = r3[1];
}

__device__ __forceinline__ f32x16 load_bias(const float* __restrict__ bp, int h) {
  f32x16 c;
#pragma unroll
  for (int b = 0; b < 4; ++b) {
    float4 t = *reinterpret_cast<const float4*>(bp + 8 * b + 4 * h);
    c[4 * b + 0] = t.x; c[4 * b + 1] = t.y; c[4 * b + 2] = t.z; c[4 * b + 3] = t.w;
  }
  return c;
}

// 4 channels (h: ch4h..4h+3) of bilinear-wrap sample of an 8-ch 512x512 tex.
__device__ __forceinline__ float4 bilin4(const float* __restrict__ tex, float ux,
                                         float uy, int h) {
  float px = ux * 512.0f - 0.5f;
  float py = uy * 512.0f - 0.5f;
  float fpx = floorf(px), fpy = floorf(py);
  float fx = px - fpx, fy = py - fpy;
  int ix = (int)fpx, iy = (int)fpy;
  int x0 = ix & 511, x1 = (ix + 1) & 511;
  int y0 = iy & 511, y1 = (iy + 1) & 511;
  const float* base = tex + (h << 2);
  float4 a = *reinterpret_cast<const float4*>(base + (size_t)(((y0 << 9) | x0) << 3));
  float4 b = *reinterpret_cast<const float4*>(base + (size_t)(((y0 << 9) | x1) << 3));
  float4 c = *reinterpret_cast<const float4*>(base + (size_t)(((y1 << 9) | x0) << 3));
  float4 d = *reinterpret_cast<const float4*>(base + (size_t)(((y1 << 9) | x1) << 3));
  float gx = 1.0f - fx, gy = 1.0f - fy;
  float w00 = gx * gy, w01 = fx * gy, w10 = gx * fy, w11 = fx * fy;
  float4 o;
  o.x = fmaf(d.x, w11, fmaf(c.x, w10, fmaf(b.x, w01, a.x * w00)));
  o.y = fmaf(d.y, w11, fmaf(c.y, w10, fmaf(b.y, w01, a.y * w00)));
  o.z = fmaf(d.z, w11, fmaf(c.z, w10, fmaf(b.z, w01, a.z * w00)));
  o.w = fmaf(d.w, w11, fmaf(c.w, w10, fmaf(b.w, w01, a.w * w00)));
  return o;
}

__global__ void __launch_bounds__(256, 4) neumip_mfma(
    const float* __restrict__ cam_g, const float* __restrict__ light_g,
    const float* __restrict__ uv_g, const float* __restrict__ offset_tex,
    const float* __restrict__ rgb_tex,
    const float* __restrict__ ow0, const float* __restrict__ ob0,
    const float* __restrict__ ow1, const float* __restrict__ ob1,
    const float* __restrict__ ow2, const float* __restrict__ ob2,
    const float* __restrict__ ow3, const float* __restrict__ ob3,
    const float* __restrict__ rw0, const float* __restrict__ rb0,
    const float* __restrict__ rw1, const float* __restrict__ rb1,
    const float* __restrict__ rw2, const float* __restrict__ rb2,
    const float* __restrict__ rw3, const float* __restrict__ rb3,
    float* __restrict__ out) {
  const int tid = threadIdx.x;
  const int lane = tid & 63;
  const int widx = tid >> 6;
  const int h = lane >> 5;
  const int sl = lane & 31;
  const int m = sl;

  // Shuffle-based output redistribution constants (lane-invariant across loop).
  const int s1 = lane / 3, c1 = lane - 3 * s1;  // for og[lane]
  const int j2 = 64 + sl;
  const int s2 = j2 / 3, c2 = j2 - 3 * s2;      // for og[64+sl]

  // ---------------- weight preload (bf16 A-frags) ----------------
  u32x4 A_o1;
  if (h == 0) {
    A_o1 = pack8(ow0 + 10 * m);
  } else {
    const float* p = ow0 + 10 * m + 8;
    A_o1 = u32x4{pkbf(p[0], p[1]), 0u, 0u, 0u};
  }
  u32x4 A_o2a = pack8(ow1 + 32 * m + 8 * h);
  u32x4 A_o2b = pack8(ow1 + 32 * m + 16 + 8 * h);
  u32x4 A_o3a = pack8(ow2 + 32 * m + 8 * h);
  u32x4 A_o3b = pack8(ow2 + 32 * m + 16 + 8 * h);

  f32x16 w3f;
#pragma unroll
  for (int b = 0; b < 4; ++b) {
    float4 t = *reinterpret_cast<const float4*>(ow3 + 8 * b + 4 * h);
    w3f[4 * b + 0] = t.x; w3f[4 * b + 1] = t.y;
    w3f[4 * b + 2] = t.z; w3f[4 * b + 3] = t.w;
  }

  u32x4 A_r1;
  if (h == 0) {
    A_r1 = pack8(rw0 + 12 * m);
  } else {
    const float* p = rw0 + 12 * m + 8;
    A_r1 = u32x4{pkbf(p[0], p[1]), pkbf(p[2], p[3]), 0u, 0u};
  }
  u32x4 A_r2a = pack8(rw1 + 32 * m + 8 * h);
  u32x4 A_r2b = pack8(rw1 + 32 * m + 16 + 8 * h);
  u32x4 A_r3a = pack8(rw2 + 32 * m + 8 * h);
  u32x4 A_r3b = pack8(rw2 + 32 * m + 16 + 8 * h);
  u32x4 A_r4a, A_r4b;
  if (m < 3) {
    A_r4a = pack8(rw3 + 32 * m + 8 * h);
    A_r4b = pack8(rw3 + 32 * m + 16 + 8 * h);
  } else {
    A_r4a = u32x4{0u, 0u, 0u, 0u};
    A_r4b = u32x4{0u, 0u, 0u, 0u};
  }
  const float b30 = rb3[0], b31 = rb3[1], b32 = rb3[2];
  const float ob3s = ob3[0];

  // ---------------- grid-stride over 32-sample groups ----------------
  const int NG = BATCH / 32;
  const int nw = (int)(gridDim.x * (blockDim.x >> 6));
  int g = (int)blockIdx.x * (int)(blockDim.x >> 6) + widx;
#pragma unroll 1
  for (; g < NG; g += nw) {
    const int S = g * 32 + sl;
    float2 uvv = reinterpret_cast<const float2*>(uv_g)[S];
    float2 cam = reinterpret_cast<const float2*>(cam_g)[S];
    float2 light = reinterpret_cast<const float2*>(light_g)[S];

    // ---- offset-branch input B-frag ----
    float4 ch = bilin4(offset_tex, uvv.x, uvv.y, h);
    unsigned V0 = pkbf(ch.x, ch.y), V1 = pkbf(ch.z, ch.w);
    auto t0 = __builtin_amdgcn_permlane32_swap(V0, V0, false, false);
    auto t1 = __builtin_amdgcn_permlane32_swap(V1, V1, false, false);
    unsigned camk = pkbf(cam.x, cam.y);
    u32x4 Bin;
    Bin[0] = h ? camk : V0;
    Bin[1] = h ? 0u : V1;
    Bin[2] = h ? 0u : t0[1];
    Bin[3] = h ? 0u : t1[1];

    // ---- offset MLP ----
    f32x16 acc = load_bias(ob0, h);
    acc = mfma_bf16(A_o1, Bin, acc);
    u32x4 B0, B1;
    act_pack_swap(acc, B0, B1);
    acc = load_bias(ob1, h);
    acc = mfma_bf16(A_o2a, B0, acc);
    acc = mfma_bf16(A_o2b, B1, acc);
    act_pack_swap(acc, B0, B1);
    acc = load_bias(ob2, h);
    acc = mfma_bf16(A_o3a, B0, acc);
    acc = mfma_bf16(A_o3b, B1, acc);

    float part = 0.0f;
#pragma unroll
    for (int i = 0; i < 16; ++i) {
      float t = acc[i];
      t = fmaxf(t, 0.01f * t);
      part = fmaf(w3f[i], t, part);
    }
    float depth = part + __shfl_xor(part, 32) + ob3s;

    // ---- displacement ----
    float s2f = fmaf(cam.x, cam.x, cam.y * cam.y);
    float z = sqrtf(fmaxf(1.0f - s2f, 1e-6f));
    float drz = depth * (1.0f / z);
    float u2x = fmaf(cam.x, drz, uvv.x);
    float u2y = fmaf(cam.y, drz, uvv.y);

    // ---- rgb-branch input B-frag ----
    float4 chr = bilin4(rgb_tex, u2x, u2y, h);
    unsigned P0 = pkbf(chr.x, chr.y), P1 = pkbf(chr.z, chr.w);
    u32x4 Brin;
    Brin[0] = h ? P0 : pkbf(light.x, light.y);
    Brin[1] = h ? P1 : camk;
    Brin[2] = h ? 0u : P0;
    Brin[3] = h ? 0u : P1;

    // ---- rgb MLP ----
    acc = load_bias(rb0, h);
    acc = mfma_bf16(A_r1, Brin, acc);
    act_pack_swap(acc, B0, B1);
    acc = load_bias(rb1, h);
    acc = mfma_bf16(A_r2a, B0, acc);
    acc = mfma_bf16(A_r2b, B1, acc);
    act_pack_swap(acc, B0, B1);
    acc = load_bias(rb2, h);
    acc = mfma_bf16(A_r3a, B0, acc);
    acc = mfma_bf16(A_r3b, B1, acc);
    act_pack_swap(acc, B0, B1);
    f32x16 accf;
#pragma unroll
    for (int i = 0; i < 16; ++i) accf[i] = 0.0f;
    accf = mfma_bf16(A_r4a, B0, accf);
    accf = mfma_bf16(A_r4b, B1, accf);

    // ---- shuffle-packed coalesced store (race-free, no LDS) ----
    float o0 = accf[0] + b30, o1 = accf[1] + b31, o2 = accf[2] + b32;
    float a0 = __shfl(o0, s1), a1 = __shfl(o1, s1), a2 = __shfl(o2, s1);
    float v1 = (c1 == 0) ? a0 : ((c1 == 1) ? a1 : a2);
    float d0 = __shfl(o0, s2), d1 = __shfl(o1, s2), d2 = __shfl(o2, s2);
    float v2 = (c2 == 0) ? d0 : ((c2 == 1) ? d1 : d2);
    float* og = out + (size_t)g * 96;
    og[lane] = v1;
    if (h == 1) og[64 + sl] = v2;
  }
}

extern "C" void kernel_launch(void* const* d_in, const int* in_sizes, int n_in,
                              void* d_out, int out_size, void* d_ws, size_t ws_size,
                              hipStream_t stream) {
  const float* cam = (const float*)d_in[0];
  const float* light = (const float*)d_in[1];
  const float* uv = (const float*)d_in[2];
  const float* offset_tex = (const float*)d_in[3];
  const float* rgb_tex = (const float*)d_in[4];
  const float* ow0 = (const float*)d_in[5];
  const float* ob0 = (const float*)d_in[6];
  const float* ow1 = (const float*)d_in[7];
  const float* ob1 = (const float*)d_in[8];
  const float* ow2 = (const float*)d_in[9];
  const float* ob2 = (const float*)d_in[10];
  const float* ow3 = (const float*)d_in[11];
  const float* ob3 = (const float*)d_in[12];
  const float* rw0 = (const float*)d_in[13];
  const float* rb0 = (const float*)d_in[14];
  const float* rw1 = (const float*)d_in[15];
  const float* rb1 = (const float*)d_in[16];
  const float* rw2 = (const float*)d_in[17];
  const float* rb2 = (const float*)d_in[18];
  const float* rw3 = (const float*)d_in[19];
  const float* rb3 = (const float*)d_in[20];
  float* out = (float*)d_out;

  dim3 grid(2048), block(256);
  hipLaunchKernelGGL(neumip_mfma, grid, block, 0, stream, cam, light, uv,
                     offset_tex, rgb_tex, ow0, ob0, ow1, ob1, ow2, ob2, ow3,
                     ob3, rw0, rb0, rw1, rb1, rw2, rb2, rw3, rb3, out);
}

// Round 8
// 295.186 us; speedup vs baseline: 1.3551x; 1.1568x over previous
//
#include <hip/hip_runtime.h>
#include <hip/hip_bf16.h>

static constexpr int BATCH = 1 << 20;
static constexpr size_t ILV_BYTES = (size_t)512 * 512 * 16 * 4;  // 16 MiB

using f32x16 = __attribute__((ext_vector_type(16))) float;
using s16x8  = __attribute__((ext_vector_type(8))) short;
using u32x4  = __attribute__((ext_vector_type(4))) unsigned int;

__device__ __forceinline__ unsigned pkbf(float lo, float hi) {
  unsigned short a = __builtin_bit_cast(unsigned short, __float2bfloat16(lo));
  unsigned short b = __builtin_bit_cast(unsigned short, __float2bfloat16(hi));
  return (unsigned)a | ((unsigned)b << 16);
}

__device__ __forceinline__ u32x4 pack8(const float* __restrict__ p) {
  u32x4 r = {pkbf(p[0], p[1]), pkbf(p[2], p[3]), pkbf(p[4], p[5]), pkbf(p[6], p[7])};
  return r;
}

__device__ __forceinline__ f32x16 mfma_bf16(u32x4 a, u32x4 b, f32x16 c) {
  return __builtin_amdgcn_mfma_f32_32x32x16_bf16(
      __builtin_bit_cast(s16x8, a), __builtin_bit_cast(s16x8, b), c, 0, 0, 0);
}

// D(f32x16) -> leaky -> bf16 B-frags for next layer (K=32).
__device__ __forceinline__ void act_pack_swap(f32x16 acc, u32x4& B0, u32x4& B1) {
  float r[16];
#pragma unroll
  for (int i = 0; i < 16; ++i) {
    float t = acc[i];
    r[i] = fmaxf(t, 0.01f * t);
  }
  unsigned pk[4][2];
#pragma unroll
  for (int b = 0; b < 4; ++b) {
    pk[b][0] = pkbf(r[4 * b + 0], r[4 * b + 1]);
    pk[b][1] = pkbf(r[4 * b + 2], r[4 * b + 3]);
  }
  auto r0 = __builtin_amdgcn_permlane32_swap(pk[0][0], pk[1][0], false, false);
  auto r1 = __builtin_amdgcn_permlane32_swap(pk[0][1], pk[1][1], false, false);
  auto r2 = __builtin_amdgcn_permlane32_swap(pk[2][0], pk[3][0], false, false);
  auto r3 = __builtin_amdgcn_permlane32_swap(pk[2][1], pk[3][1], false, false);
  B0[0] = r0[0]; B0[1] = r1[0]; B0[2] = r0[1]; B0[3] = r1[1];
  B1[0] = r2[0]; B1[1] = r3[0]; B1[2] = r2[1]; B1[3] = r3[1];
}

__device__ __forceinline__ f32x16 load_bias(const float* __restrict__ bp, int h) {
  f32x16 c;
#pragma unroll
  for (int b = 0; b < 4; ++b) {
    float4 t = *reinterpret_cast<const float4*>(bp + 8 * b + 4 * h);
    c[4 * b + 0] = t.x; c[4 * b + 1] = t.y; c[4 * b + 2] = t.z; c[4 * b + 3] = t.w;
  }
  return c;
}

// 4 channels (h: ch4h..4h+3) of bilinear-wrap sample. which: 0=offset,1=rgb.
// ILV: tex is the 16-ch interleaved texture (64B/texel); else the raw 8-ch one.
template <bool ILV>
__device__ __forceinline__ float4 bilin4(const float* __restrict__ tex, float ux,
                                         float uy, int h, int which) {
  float px = ux * 512.0f - 0.5f;
  float py = uy * 512.0f - 0.5f;
  float fpx = floorf(px), fpy = floorf(py);
  float fx = px - fpx, fy = py - fpy;
  int ix = (int)fpx, iy = (int)fpy;
  int x0 = ix & 511, x1 = (ix + 1) & 511;
  int y0 = iy & 511, y1 = (iy + 1) & 511;
  constexpr int SH = ILV ? 4 : 3;
  const int co = (ILV ? (which << 3) : 0) + (h << 2);
  const float* p00 = tex + (((size_t)((y0 << 9) | x0) << SH) + co);
  const float* p01 = tex + (((size_t)((y0 << 9) | x1) << SH) + co);
  const float* p10 = tex + (((size_t)((y1 << 9) | x0) << SH) + co);
  const float* p11 = tex + (((size_t)((y1 << 9) | x1) << SH) + co);
  float4 a = *reinterpret_cast<const float4*>(p00);
  float4 b = *reinterpret_cast<const float4*>(p01);
  float4 c = *reinterpret_cast<const float4*>(p10);
  float4 d = *reinterpret_cast<const float4*>(p11);
  float gx = 1.0f - fx, gy = 1.0f - fy;
  float w00 = gx * gy, w01 = fx * gy, w10 = gx * fy, w11 = fx * fy;
  float4 o;
  o.x = fmaf(d.x, w11, fmaf(c.x, w10, fmaf(b.x, w01, a.x * w00)));
  o.y = fmaf(d.y, w11, fmaf(c.y, w10, fmaf(b.y, w01, a.y * w00)));
  o.z = fmaf(d.z, w11, fmaf(c.z, w10, fmaf(b.z, w01, a.z * w00)));
  o.w = fmaf(d.w, w11, fmaf(c.w, w10, fmaf(b.w, w01, a.w * w00)));
  return o;
}

// Build interleaved texture: ws[texel][0:8]=offset ch, ws[texel][8:16]=rgb ch.
__global__ void __launch_bounds__(256) tex_interleave(
    const float* __restrict__ t0, const float* __restrict__ t1,
    float* __restrict__ ws) {
  int i = blockIdx.x * 256 + threadIdx.x;  // one float4 slot each; 1M slots
  int texel = i >> 2;
  int q = i & 3;
  const float* src = (q < 2 ? t0 : t1) + (((size_t)texel << 3) + ((q & 1) << 2));
  reinterpret_cast<float4*>(ws)[i] = *reinterpret_cast<const float4*>(src);
}

template <bool ILV>
__global__ void __launch_bounds__(256, 3) neumip_mfma(
    const float* __restrict__ cam_g, const float* __restrict__ light_g,
    const float* __restrict__ uv_g, const float* __restrict__ offset_tex,
    const float* __restrict__ rgb_tex, const float* __restrict__ wtex,
    const float* __restrict__ ow0, const float* __restrict__ ob0,
    const float* __restrict__ ow1, const float* __restrict__ ob1,
    const float* __restrict__ ow2, const float* __restrict__ ob2,
    const float* __restrict__ ow3, const float* __restrict__ ob3,
    const float* __restrict__ rw0, const float* __restrict__ rb0,
    const float* __restrict__ rw1, const float* __restrict__ rb1,
    const float* __restrict__ rw2, const float* __restrict__ rb2,
    const float* __restrict__ rw3, const float* __restrict__ rb3,
    float* __restrict__ out) {
  const int tid = threadIdx.x;
  const int lane = tid & 63;
  const int widx = tid >> 6;
  const int h = lane >> 5;
  const int sl = lane & 31;
  const int m = sl;
  const float* texO = ILV ? wtex : offset_tex;
  const float* texR = ILV ? wtex : rgb_tex;

  // Shuffle-based output redistribution constants (lane-invariant across loop).
  const int s1 = lane / 3, c1 = lane - 3 * s1;  // for og[lane]
  const int j2 = 64 + sl;
  const int s2 = j2 / 3, c2 = j2 - 3 * s2;      // for og[64+sl]

  // ---------------- weight preload (bf16 A-frags) ----------------
  u32x4 A_o1;
  if (h == 0) {
    A_o1 = pack8(ow0 + 10 * m);
  } else {
    const float* p = ow0 + 10 * m + 8;
    A_o1 = u32x4{pkbf(p[0], p[1]), 0u, 0u, 0u};
  }
  u32x4 A_o2a = pack8(ow1 + 32 * m + 8 * h);
  u32x4 A_o2b = pack8(ow1 + 32 * m + 16 + 8 * h);
  u32x4 A_o3a = pack8(ow2 + 32 * m + 8 * h);
  u32x4 A_o3b = pack8(ow2 + 32 * m + 16 + 8 * h);

  f32x16 w3f;
#pragma unroll
  for (int b = 0; b < 4; ++b) {
    float4 t = *reinterpret_cast<const float4*>(ow3 + 8 * b + 4 * h);
    w3f[4 * b + 0] = t.x; w3f[4 * b + 1] = t.y;
    w3f[4 * b + 2] = t.z; w3f[4 * b + 3] = t.w;
  }

  u32x4 A_r1;
  if (h == 0) {
    A_r1 = pack8(rw0 + 12 * m);
  } else {
    const float* p = rw0 + 12 * m + 8;
    A_r1 = u32x4{pkbf(p[0], p[1]), pkbf(p[2], p[3]), 0u, 0u};
  }
  u32x4 A_r2a = pack8(rw1 + 32 * m + 8 * h);
  u32x4 A_r2b = pack8(rw1 + 32 * m + 16 + 8 * h);
  u32x4 A_r3a = pack8(rw2 + 32 * m + 8 * h);
  u32x4 A_r3b = pack8(rw2 + 32 * m + 16 + 8 * h);
  u32x4 A_r4a, A_r4b;
  if (m < 3) {
    A_r4a = pack8(rw3 + 32 * m + 8 * h);
    A_r4b = pack8(rw3 + 32 * m + 16 + 8 * h);
  } else {
    A_r4a = u32x4{0u, 0u, 0u, 0u};
    A_r4b = u32x4{0u, 0u, 0u, 0u};
  }
  const float b30 = rb3[0], b31 = rb3[1], b32 = rb3[2];
  const float ob3s = ob3[0];

  // ---------------- grid-stride over 32-sample groups ----------------
  const int NG = BATCH / 32;
  const int nw = (int)(gridDim.x * (blockDim.x >> 6));
  int g = (int)blockIdx.x * (int)(blockDim.x >> 6) + widx;
#pragma unroll 1
  for (; g < NG; g += nw) {
    const int S = g * 32 + sl;
    float2 uvv = reinterpret_cast<const float2*>(uv_g)[S];
    float2 cam = reinterpret_cast<const float2*>(cam_g)[S];
    float2 light = reinterpret_cast<const float2*>(light_g)[S];

    // ---- offset-branch input B-frag ----
    float4 ch = bilin4<ILV>(texO, uvv.x, uvv.y, h, 0);
    unsigned V0 = pkbf(ch.x, ch.y), V1 = pkbf(ch.z, ch.w);
    auto t0 = __builtin_amdgcn_permlane32_swap(V0, V0, false, false);
    auto t1 = __builtin_amdgcn_permlane32_swap(V1, V1, false, false);
    unsigned camk = pkbf(cam.x, cam.y);
    u32x4 Bin;
    Bin[0] = h ? camk : V0;
    Bin[1] = h ? 0u : V1;
    Bin[2] = h ? 0u : t0[1];
    Bin[3] = h ? 0u : t1[1];

    // ---- offset MLP ----
    f32x16 acc = load_bias(ob0, h);
    acc = mfma_bf16(A_o1, Bin, acc);
    u32x4 B0, B1;
    act_pack_swap(acc, B0, B1);
    acc = load_bias(ob1, h);
    acc = mfma_bf16(A_o2a, B0, acc);
    acc = mfma_bf16(A_o2b, B1, acc);
    act_pack_swap(acc, B0, B1);
    acc = load_bias(ob2, h);
    acc = mfma_bf16(A_o3a, B0, acc);
    acc = mfma_bf16(A_o3b, B1, acc);

    float part = 0.0f;
#pragma unroll
    for (int i = 0; i < 16; ++i) {
      float t = acc[i];
      t = fmaxf(t, 0.01f * t);
      part = fmaf(w3f[i], t, part);
    }
    float depth = part + __shfl_xor(part, 32) + ob3s;

    // ---- displacement ----
    float s2f = fmaf(cam.x, cam.x, cam.y * cam.y);
    float z = sqrtf(fmaxf(1.0f - s2f, 1e-6f));
    float drz = depth * (1.0f / z);
    float u2x = fmaf(cam.x, drz, uvv.x);
    float u2y = fmaf(cam.y, drz, uvv.y);

    // ---- rgb-branch input B-frag ----
    float4 chr = bilin4<ILV>(texR, u2x, u2y, h, 1);
    unsigned P0 = pkbf(chr.x, chr.y), P1 = pkbf(chr.z, chr.w);
    u32x4 Brin;
    Brin[0] = h ? P0 : pkbf(light.x, light.y);
    Brin[1] = h ? P1 : camk;
    Brin[2] = h ? 0u : P0;
    Brin[3] = h ? 0u : P1;

    // ---- rgb MLP ----
    acc = load_bias(rb0, h);
    acc = mfma_bf16(A_r1, Brin, acc);
    act_pack_swap(acc, B0, B1);
    acc = load_bias(rb1, h);
    acc = mfma_bf16(A_r2a, B0, acc);
    acc = mfma_bf16(A_r2b, B1, acc);
    act_pack_swap(acc, B0, B1);
    acc = load_bias(rb2, h);
    acc = mfma_bf16(A_r3a, B0, acc);
    acc = mfma_bf16(A_r3b, B1, acc);
    act_pack_swap(acc, B0, B1);
    f32x16 accf;
#pragma unroll
    for (int i = 0; i < 16; ++i) accf[i] = 0.0f;
    accf = mfma_bf16(A_r4a, B0, accf);
    accf = mfma_bf16(A_r4b, B1, accf);

    // ---- shuffle-packed coalesced store (race-free, no LDS) ----
    float o0 = accf[0] + b30, o1 = accf[1] + b31, o2 = accf[2] + b32;
    float a0 = __shfl(o0, s1), a1 = __shfl(o1, s1), a2 = __shfl(o2, s1);
    float v1 = (c1 == 0) ? a0 : ((c1 == 1) ? a1 : a2);
    float d0 = __shfl(o0, s2), d1 = __shfl(o1, s2), d2 = __shfl(o2, s2);
    float v2 = (c2 == 0) ? d0 : ((c2 == 1) ? d1 : d2);
    float* og = out + (size_t)g * 96;
    og[lane] = v1;
    if (h == 1) og[64 + sl] = v2;
  }
}

extern "C" void kernel_launch(void* const* d_in, const int* in_sizes, int n_in,
                              void* d_out, int out_size, void* d_ws, size_t ws_size,
                              hipStream_t stream) {
  const float* cam = (const float*)d_in[0];
  const float* light = (const float*)d_in[1];
  const float* uv = (const float*)d_in[2];
  const float* offset_tex = (const float*)d_in[3];
  const float* rgb_tex = (const float*)d_in[4];
  const float* ow0 = (const float*)d_in[5];
  const float* ob0 = (const float*)d_in[6];
  const float* ow1 = (const float*)d_in[7];
  const float* ob1 = (const float*)d_in[8];
  const float* ow2 = (const float*)d_in[9];
  const float* ob2 = (const float*)d_in[10];
  const float* ow3 = (const float*)d_in[11];
  const float* ob3 = (const float*)d_in[12];
  const float* rw0 = (const float*)d_in[13];
  const float* rb0 = (const float*)d_in[14];
  const float* rw1 = (const float*)d_in[15];
  const float* rb1 = (const float*)d_in[16];
  const float* rw2 = (const float*)d_in[17];
  const float* rb2 = (const float*)d_in[18];
  const float* rw3 = (const float*)d_in[19];
  const float* rb3 = (const float*)d_in[20];
  float* out = (float*)d_out;
  float* wtex = (float*)d_ws;

  dim3 block(256);
  if (ws_size >= ILV_BYTES) {
    hipLaunchKernelGGL(tex_interleave, dim3(4096), block, 0, stream, offset_tex,
                       rgb_tex, wtex);
    hipLaunchKernelGGL(neumip_mfma<true>, dim3(2048), block, 0, stream, cam,
                       light, uv, offset_tex, rgb_tex, wtex, ow0, ob0, ow1, ob1,
                       ow2, ob2, ow3, ob3, rw0, rb0, rw1, rb1, rw2, rb2, rw3,
                       rb3, out);
  } else {
    hipLaunchKernelGGL(neumip_mfma<false>, dim3(2048), block, 0, stream, cam,
                       light, uv, offset_tex, rgb_tex, wtex, ow0, ob0, ow1, ob1,
                       ow2, ob2, ow3, ob3, rw0, rb0, rw1, rb1, rw2, rb2, rw3,
                       rb3, out);
  }
}

// Round 9
// 277.067 us; speedup vs baseline: 1.4437x; 1.0654x over previous
//
#include <hip/hip_runtime.h>
#include <hip/hip_bf16.h>

static constexpr int BATCH = 1 << 20;
static constexpr size_t ILV_BYTES = (size_t)512 * 512 * 16 * 4;  // 16 MiB
static constexpr size_t WBLOB_BYTES = 768 * 16;                  // 12 KiB

using f32x16 = __attribute__((ext_vector_type(16))) float;
using s16x8  = __attribute__((ext_vector_type(8))) short;
using u32x4  = __attribute__((ext_vector_type(4))) unsigned int;

__device__ __forceinline__ unsigned pkbf(float lo, float hi) {
  unsigned short a = __builtin_bit_cast(unsigned short, __float2bfloat16(lo));
  unsigned short b = __builtin_bit_cast(unsigned short, __float2bfloat16(hi));
  return (unsigned)a | ((unsigned)b << 16);
}

__device__ __forceinline__ u32x4 pack8(const float* __restrict__ p) {
  u32x4 r = {pkbf(p[0], p[1]), pkbf(p[2], p[3]), pkbf(p[4], p[5]), pkbf(p[6], p[7])};
  return r;
}

__device__ __forceinline__ f32x16 mfma_bf16(u32x4 a, u32x4 b, f32x16 c) {
  return __builtin_amdgcn_mfma_f32_32x32x16_bf16(
      __builtin_bit_cast(s16x8, a), __builtin_bit_cast(s16x8, b), c, 0, 0, 0);
}

// D(f32x16) -> leaky -> bf16 B-frags for next layer (K=32).
__device__ __forceinline__ void act_pack_swap(f32x16 acc, u32x4& B0, u32x4& B1) {
  float r[16];
#pragma unroll
  for (int i = 0; i < 16; ++i) {
    float t = acc[i];
    r[i] = fmaxf(t, 0.01f * t);
  }
  unsigned pk[4][2];
#pragma unroll
  for (int b = 0; b < 4; ++b) {
    pk[b][0] = pkbf(r[4 * b + 0], r[4 * b + 1]);
    pk[b][1] = pkbf(r[4 * b + 2], r[4 * b + 3]);
  }
  auto r0 = __builtin_amdgcn_permlane32_swap(pk[0][0], pk[1][0], false, false);
  auto r1 = __builtin_amdgcn_permlane32_swap(pk[0][1], pk[1][1], false, false);
  auto r2 = __builtin_amdgcn_permlane32_swap(pk[2][0], pk[3][0], false, false);
  auto r3 = __builtin_amdgcn_permlane32_swap(pk[2][1], pk[3][1], false, false);
  B0[0] = r0[0]; B0[1] = r1[0]; B0[2] = r0[1]; B0[3] = r1[1];
  B1[0] = r2[0]; B1[1] = r3[0]; B1[2] = r2[1]; B1[3] = r3[1];
}

__device__ __forceinline__ f32x16 load_bias(const float* __restrict__ bp, int h) {
  f32x16 c;
#pragma unroll
  for (int b = 0; b < 4; ++b) {
    float4 t = *reinterpret_cast<const float4*>(bp + 8 * b + 4 * h);
    c[4 * b + 0] = t.x; c[4 * b + 1] = t.y; c[4 * b + 2] = t.z; c[4 * b + 3] = t.w;
  }
  return c;
}

// 4 channels (h: ch4h..4h+3) of bilinear-wrap sample. which: 0=offset,1=rgb.
template <bool ILV>
__device__ __forceinline__ float4 bilin4(const float* __restrict__ tex, float ux,
                                         float uy, int h, int which) {
  float px = ux * 512.0f - 0.5f;
  float py = uy * 512.0f - 0.5f;
  float fpx = floorf(px), fpy = floorf(py);
  float fx = px - fpx, fy = py - fpy;
  int ix = (int)fpx, iy = (int)fpy;
  int x0 = ix & 511, x1 = (ix + 1) & 511;
  int y0 = iy & 511, y1 = (iy + 1) & 511;
  constexpr int SH = ILV ? 4 : 3;
  const int co = (ILV ? (which << 3) : 0) + (h << 2);
  const float* p00 = tex + (((size_t)((y0 << 9) | x0) << SH) + co);
  const float* p01 = tex + (((size_t)((y0 << 9) | x1) << SH) + co);
  const float* p10 = tex + (((size_t)((y1 << 9) | x0) << SH) + co);
  const float* p11 = tex + (((size_t)((y1 << 9) | x1) << SH) + co);
  float4 a = *reinterpret_cast<const float4*>(p00);
  float4 b = *reinterpret_cast<const float4*>(p01);
  float4 c = *reinterpret_cast<const float4*>(p10);
  float4 d = *reinterpret_cast<const float4*>(p11);
  float gx = 1.0f - fx, gy = 1.0f - fy;
  float w00 = gx * gy, w01 = fx * gy, w10 = gx * fy, w11 = fx * fy;
  float4 o;
  o.x = fmaf(d.x, w11, fmaf(c.x, w10, fmaf(b.x, w01, a.x * w00)));
  o.y = fmaf(d.y, w11, fmaf(c.y, w10, fmaf(b.y, w01, a.y * w00)));
  o.z = fmaf(d.z, w11, fmaf(c.z, w10, fmaf(b.z, w01, a.z * w00)));
  o.w = fmaf(d.w, w11, fmaf(c.w, w10, fmaf(b.w, w01, a.w * w00)));
  return o;
}

// Build interleaved texture: ws[texel][0:8]=offset ch, ws[texel][8:16]=rgb ch.
__global__ void __launch_bounds__(256) tex_interleave(
    const float* __restrict__ t0, const float* __restrict__ t1,
    float* __restrict__ ws) {
  int i = blockIdx.x * 256 + threadIdx.x;  // one float4 slot each; 1M slots
  int texel = i >> 2;
  int q = i & 3;
  const float* src = (q < 2 ? t0 : t1) + (((size_t)texel << 3) + ((q & 1) << 2));
  reinterpret_cast<float4*>(ws)[i] = *reinterpret_cast<const float4*>(src);
}

// Pre-pack all MFMA A-fragments (bf16) into a 12 KiB blob.
// Layout: slot = (h*32+m)*12 + F, F in {o1,o2a,o2b,o3a,o3b,r1,r2a,r2b,r3a,r3b,r4a,r4b}.
__global__ void __launch_bounds__(256) pack_weights(
    const float* __restrict__ ow0, const float* __restrict__ ow1,
    const float* __restrict__ ow2, const float* __restrict__ rw0,
    const float* __restrict__ rw1, const float* __restrict__ rw2,
    const float* __restrict__ rw3, u32x4* __restrict__ Wb) {
  for (int slot = threadIdx.x; slot < 768; slot += 256) {
    int F = slot % 12;
    int lb = slot / 12;
    int h = lb >> 5, m = lb & 31;
    u32x4 v = {0u, 0u, 0u, 0u};
    switch (F) {
      case 0:
        if (h == 0) v = pack8(ow0 + 10 * m);
        else { const float* p = ow0 + 10 * m + 8; v = u32x4{pkbf(p[0], p[1]), 0u, 0u, 0u}; }
        break;
      case 1: v = pack8(ow1 + 32 * m + 8 * h); break;
      case 2: v = pack8(ow1 + 32 * m + 16 + 8 * h); break;
      case 3: v = pack8(ow2 + 32 * m + 8 * h); break;
      case 4: v = pack8(ow2 + 32 * m + 16 + 8 * h); break;
      case 5:
        if (h == 0) v = pack8(rw0 + 12 * m);
        else { const float* p = rw0 + 12 * m + 8; v = u32x4{pkbf(p[0], p[1]), pkbf(p[2], p[3]), 0u, 0u}; }
        break;
      case 6: v = pack8(rw1 + 32 * m + 8 * h); break;
      case 7: v = pack8(rw1 + 32 * m + 16 + 8 * h); break;
      case 8: v = pack8(rw2 + 32 * m + 8 * h); break;
      case 9: v = pack8(rw2 + 32 * m + 16 + 8 * h); break;
      case 10: if (m < 3) v = pack8(rw3 + 32 * m + 8 * h); break;
      case 11: if (m < 3) v = pack8(rw3 + 32 * m + 16 + 8 * h); break;
    }
    Wb[slot] = v;
  }
}

// ILV=true: wtex is the 16-ch interleaved texture AND Wb holds prepacked frags.
// ILV=false: fully self-contained fallback (raw textures, in-kernel packing).
template <bool ILV>
__global__ void __launch_bounds__(256, 3) neumip_mfma(
    const float* __restrict__ cam_g, const float* __restrict__ light_g,
    const float* __restrict__ uv_g, const float* __restrict__ offset_tex,
    const float* __restrict__ rgb_tex, const float* __restrict__ wtex,
    const u32x4* __restrict__ Wb,
    const float* __restrict__ ow0, const float* __restrict__ ob0,
    const float* __restrict__ ow1, const float* __restrict__ ob1,
    const float* __restrict__ ow2, const float* __restrict__ ob2,
    const float* __restrict__ ow3, const float* __restrict__ ob3,
    const float* __restrict__ rw0, const float* __restrict__ rb0,
    const float* __restrict__ rw1, const float* __restrict__ rb1,
    const float* __restrict__ rw2, const float* __restrict__ rb2,
    const float* __restrict__ rw3, const float* __restrict__ rb3,
    float* __restrict__ out) {
  const int tid = threadIdx.x;
  const int lane = tid & 63;
  const int widx = tid >> 6;
  const int h = lane >> 5;
  const int sl = lane & 31;
  const int m = sl;
  const float* texO = ILV ? wtex : offset_tex;
  const float* texR = ILV ? wtex : rgb_tex;

  // Shuffle-based output redistribution constants.
  const int s1 = lane / 3, c1 = lane - 3 * s1;  // for og[lane]
  const int j2 = 64 + sl;
  const int s2 = j2 / 3, c2 = j2 - 3 * s2;      // for og[64+sl]

  // ---------------- weight fragments ----------------
  // ILV: pure loads from the prepacked blob (rematerializable under pressure ->
  // no scratch). Fallback: in-register pack (round-2 behavior).
  const u32x4* Wl = Wb + (h * 32 + m) * 12;
  u32x4 A_o1, A_o2a, A_o2b, A_o3a, A_o3b, A_r1, A_r2a, A_r2b, A_r3a, A_r3b,
      A_r4a, A_r4b;
  if (ILV) {
    A_o1 = Wl[0];  A_o2a = Wl[1]; A_o2b = Wl[2]; A_o3a = Wl[3]; A_o3b = Wl[4];
    A_r1 = Wl[5];  A_r2a = Wl[6]; A_r2b = Wl[7]; A_r3a = Wl[8]; A_r3b = Wl[9];
    A_r4a = Wl[10]; A_r4b = Wl[11];
  } else {
    if (h == 0) {
      A_o1 = pack8(ow0 + 10 * m);
    } else {
      const float* p = ow0 + 10 * m + 8;
      A_o1 = u32x4{pkbf(p[0], p[1]), 0u, 0u, 0u};
    }
    A_o2a = pack8(ow1 + 32 * m + 8 * h);
    A_o2b = pack8(ow1 + 32 * m + 16 + 8 * h);
    A_o3a = pack8(ow2 + 32 * m + 8 * h);
    A_o3b = pack8(ow2 + 32 * m + 16 + 8 * h);
    if (h == 0) {
      A_r1 = pack8(rw0 + 12 * m);
    } else {
      const float* p = rw0 + 12 * m + 8;
      A_r1 = u32x4{pkbf(p[0], p[1]), pkbf(p[2], p[3]), 0u, 0u};
    }
    A_r2a = pack8(rw1 + 32 * m + 8 * h);
    A_r2b = pack8(rw1 + 32 * m + 16 + 8 * h);
    A_r3a = pack8(rw2 + 32 * m + 8 * h);
    A_r3b = pack8(rw2 + 32 * m + 16 + 8 * h);
    if (m < 3) {
      A_r4a = pack8(rw3 + 32 * m + 8 * h);
      A_r4b = pack8(rw3 + 32 * m + 16 + 8 * h);
    } else {
      A_r4a = u32x4{0u, 0u, 0u, 0u};
      A_r4b = u32x4{0u, 0u, 0u, 0u};
    }
  }

  f32x16 w3f;
#pragma unroll
  for (int b = 0; b < 4; ++b) {
    float4 t = *reinterpret_cast<const float4*>(ow3 + 8 * b + 4 * h);
    w3f[4 * b + 0] = t.x; w3f[4 * b + 1] = t.y;
    w3f[4 * b + 2] = t.z; w3f[4 * b + 3] = t.w;
  }
  const float b30 = rb3[0], b31 = rb3[1], b32 = rb3[2];
  const float ob3s = ob3[0];

  // ---------------- grid-stride over 32-sample groups ----------------
  const int NG = BATCH / 32;
  const int nw = (int)(gridDim.x * (blockDim.x >> 6));
  int g = (int)blockIdx.x * (int)(blockDim.x >> 6) + widx;
#pragma unroll 1
  for (; g < NG; g += nw) {
    const int S = g * 32 + sl;
    float2 uvv = reinterpret_cast<const float2*>(uv_g)[S];
    float2 cam = reinterpret_cast<const float2*>(cam_g)[S];
    float2 light = reinterpret_cast<const float2*>(light_g)[S];

    // ---- offset-branch input B-frag ----
    float4 ch = bilin4<ILV>(texO, uvv.x, uvv.y, h, 0);
    unsigned V0 = pkbf(ch.x, ch.y), V1 = pkbf(ch.z, ch.w);
    auto t0 = __builtin_amdgcn_permlane32_swap(V0, V0, false, false);
    auto t1 = __builtin_amdgcn_permlane32_swap(V1, V1, false, false);
    unsigned camk = pkbf(cam.x, cam.y);
    u32x4 Bin;
    Bin[0] = h ? camk : V0;
    Bin[1] = h ? 0u : V1;
    Bin[2] = h ? 0u : t0[1];
    Bin[3] = h ? 0u : t1[1];

    // ---- offset MLP ----
    f32x16 acc = load_bias(ob0, h);
    acc = mfma_bf16(A_o1, Bin, acc);
    u32x4 B0, B1;
    act_pack_swap(acc, B0, B1);
    acc = load_bias(ob1, h);
    acc = mfma_bf16(A_o2a, B0, acc);
    acc = mfma_bf16(A_o2b, B1, acc);
    act_pack_swap(acc, B0, B1);
    acc = load_bias(ob2, h);
    acc = mfma_bf16(A_o3a, B0, acc);
    acc = mfma_bf16(A_o3b, B1, acc);

    float part = 0.0f;
#pragma unroll
    for (int i = 0; i < 16; ++i) {
      float t = acc[i];
      t = fmaxf(t, 0.01f * t);
      part = fmaf(w3f[i], t, part);
    }
    float depth = part + __shfl_xor(part, 32) + ob3s;

    // ---- displacement ----
    float s2f = fmaf(cam.x, cam.x, cam.y * cam.y);
    float z = sqrtf(fmaxf(1.0f - s2f, 1e-6f));
    float drz = depth * (1.0f / z);
    float u2x = fmaf(cam.x, drz, uvv.x);
    float u2y = fmaf(cam.y, drz, uvv.y);

    // ---- rgb-branch input B-frag ----
    float4 chr = bilin4<ILV>(texR, u2x, u2y, h, 1);
    unsigned P0 = pkbf(chr.x, chr.y), P1 = pkbf(chr.z, chr.w);
    u32x4 Brin;
    Brin[0] = h ? P0 : pkbf(light.x, light.y);
    Brin[1] = h ? P1 : camk;
    Brin[2] = h ? 0u : P0;
    Brin[3] = h ? 0u : P1;

    // ---- rgb MLP ----
    acc = load_bias(rb0, h);
    acc = mfma_bf16(A_r1, Brin, acc);
    act_pack_swap(acc, B0, B1);
    acc = load_bias(rb1, h);
    acc = mfma_bf16(A_r2a, B0, acc);
    acc = mfma_bf16(A_r2b, B1, acc);
    act_pack_swap(acc, B0, B1);
    acc = load_bias(rb2, h);
    acc = mfma_bf16(A_r3a, B0, acc);
    acc = mfma_bf16(A_r3b, B1, acc);
    act_pack_swap(acc, B0, B1);
    f32x16 accf;
#pragma unroll
    for (int i = 0; i < 16; ++i) accf[i] = 0.0f;
    accf = mfma_bf16(A_r4a, B0, accf);
    accf = mfma_bf16(A_r4b, B1, accf);

    // ---- shuffle-packed coalesced store ----
    float o0 = accf[0] + b30, o1 = accf[1] + b31, o2 = accf[2] + b32;
    float a0 = __shfl(o0, s1), a1 = __shfl(o1, s1), a2 = __shfl(o2, s1);
    float v1 = (c1 == 0) ? a0 : ((c1 == 1) ? a1 : a2);
    float d0 = __shfl(o0, s2), d1 = __shfl(o1, s2), d2 = __shfl(o2, s2);
    float v2 = (c2 == 0) ? d0 : ((c2 == 1) ? d1 : d2);
    float* og = out + (size_t)g * 96;
    og[lane] = v1;
    if (h == 1) og[64 + sl] = v2;
  }
}

extern "C" void kernel_launch(void* const* d_in, const int* in_sizes, int n_in,
                              void* d_out, int out_size, void* d_ws, size_t ws_size,
                              hipStream_t stream) {
  const float* cam = (const float*)d_in[0];
  const float* light = (const float*)d_in[1];
  const float* uv = (const float*)d_in[2];
  const float* offset_tex = (const float*)d_in[3];
  const float* rgb_tex = (const float*)d_in[4];
  const float* ow0 = (const float*)d_in[5];
  const float* ob0 = (const float*)d_in[6];
  const float* ow1 = (const float*)d_in[7];
  const float* ob1 = (const float*)d_in[8];
  const float* ow2 = (const float*)d_in[9];
  const float* ob2 = (const float*)d_in[10];
  const float* ow3 = (const float*)d_in[11];
  const float* ob3 = (const float*)d_in[12];
  const float* rw0 = (const float*)d_in[13];
  const float* rb0 = (const float*)d_in[14];
  const float* rw1 = (const float*)d_in[15];
  const float* rb1 = (const float*)d_in[16];
  const float* rw2 = (const float*)d_in[17];
  const float* rb2 = (const float*)d_in[18];
  const float* rw3 = (const float*)d_in[19];
  const float* rb3 = (const float*)d_in[20];
  float* out = (float*)d_out;
  float* wtex = (float*)d_ws;
  u32x4* Wb = (u32x4*)((char*)d_ws + ILV_BYTES);

  dim3 block(256);
  if (ws_size >= ILV_BYTES + WBLOB_BYTES) {
    hipLaunchKernelGGL(tex_interleave, dim3(4096), block, 0, stream, offset_tex,
                       rgb_tex, wtex);
    hipLaunchKernelGGL(pack_weights, dim3(1), block, 0, stream, ow0, ow1, ow2,
                       rw0, rw1, rw2, rw3, Wb);
    hipLaunchKernelGGL(neumip_mfma<true>, dim3(2048), block, 0, stream, cam,
                       light, uv, offset_tex, rgb_tex, wtex, Wb, ow0, ob0, ow1,
                       ob1, ow2, ob2, ow3, ob3, rw0, rb0, rw1, rb1, rw2, rb2,
                       rw3, rb3, out);
  } else {
    hipLaunchKernelGGL(neumip_mfma<false>, dim3(2048), block, 0, stream, cam,
                       light, uv, offset_tex, rgb_tex, wtex, Wb, ow0, ob0, ow1,
                       ob1, ow2, ob2, ow3, ob3, rw0, rb0, rw1, rb1, rw2, rb2,
                       rw3, rb3, out);
  }
}

// Round 10
// 205.436 us; speedup vs baseline: 1.9471x; 1.3487x over previous
//
#include <hip/hip_runtime.h>
#include <hip/hip_bf16.h>

static constexpr int BATCH = 1 << 20;
static constexpr size_t ILV_BYTES = (size_t)512 * 512 * 16 * 4;  // 16 MiB
static constexpr size_t WBLOB_BYTES = 768 * 16;                  // 12 KiB

using f32x16 = __attribute__((ext_vector_type(16))) float;
using s16x8  = __attribute__((ext_vector_type(8))) short;
using u32x4  = __attribute__((ext_vector_type(4))) unsigned int;

__device__ __forceinline__ unsigned pkbf(float lo, float hi) {
  unsigned short a = __builtin_bit_cast(unsigned short, __float2bfloat16(lo));
  unsigned short b = __builtin_bit_cast(unsigned short, __float2bfloat16(hi));
  return (unsigned)a | ((unsigned)b << 16);
}

__device__ __forceinline__ u32x4 pack8(const float* __restrict__ p) {
  u32x4 r = {pkbf(p[0], p[1]), pkbf(p[2], p[3]), pkbf(p[4], p[5]), pkbf(p[6], p[7])};
  return r;
}

__device__ __forceinline__ f32x16 mfma_bf16(u32x4 a, u32x4 b, f32x16 c) {
  return __builtin_amdgcn_mfma_f32_32x32x16_bf16(
      __builtin_bit_cast(s16x8, a), __builtin_bit_cast(s16x8, b), c, 0, 0, 0);
}

// D(f32x16) -> leaky -> bf16 B-frags for next layer (K=32).
__device__ __forceinline__ void act_pack_swap(f32x16 acc, u32x4& B0, u32x4& B1) {
  float r[16];
#pragma unroll
  for (int i = 0; i < 16; ++i) {
    float t = acc[i];
    r[i] = fmaxf(t, 0.01f * t);
  }
  unsigned pk[4][2];
#pragma unroll
  for (int b = 0; b < 4; ++b) {
    pk[b][0] = pkbf(r[4 * b + 0], r[4 * b + 1]);
    pk[b][1] = pkbf(r[4 * b + 2], r[4 * b + 3]);
  }
  auto r0 = __builtin_amdgcn_permlane32_swap(pk[0][0], pk[1][0], false, false);
  auto r1 = __builtin_amdgcn_permlane32_swap(pk[0][1], pk[1][1], false, false);
  auto r2 = __builtin_amdgcn_permlane32_swap(pk[2][0], pk[3][0], false, false);
  auto r3 = __builtin_amdgcn_permlane32_swap(pk[2][1], pk[3][1], false, false);
  B0[0] = r0[0]; B0[1] = r1[0]; B0[2] = r0[1]; B0[3] = r1[1];
  B1[0] = r2[0]; B1[1] = r3[0]; B1[2] = r2[1]; B1[3] = r3[1];
}

__device__ __forceinline__ f32x16 load_bias(const float* __restrict__ bp, int h) {
  f32x16 c;
#pragma unroll
  for (int b = 0; b < 4; ++b) {
    float4 t = *reinterpret_cast<const float4*>(bp + 8 * b + 4 * h);
    c[4 * b + 0] = t.x; c[4 * b + 1] = t.y; c[4 * b + 2] = t.z; c[4 * b + 3] = t.w;
  }
  return c;
}

// 4 channels (h: ch4h..4h+3) of bilinear-wrap sample. which: 0=offset,1=rgb.
template <bool ILV>
__device__ __forceinline__ float4 bilin4(const float* __restrict__ tex, float ux,
                                         float uy, int h, int which) {
  float px = ux * 512.0f - 0.5f;
  float py = uy * 512.0f - 0.5f;
  float fpx = floorf(px), fpy = floorf(py);
  float fx = px - fpx, fy = py - fpy;
  int ix = (int)fpx, iy = (int)fpy;
  int x0 = ix & 511, x1 = (ix + 1) & 511;
  int y0 = iy & 511, y1 = (iy + 1) & 511;
  constexpr int SH = ILV ? 4 : 3;
  const int co = (ILV ? (which << 3) : 0) + (h << 2);
  const float* p00 = tex + (((size_t)((y0 << 9) | x0) << SH) + co);
  const float* p01 = tex + (((size_t)((y0 << 9) | x1) << SH) + co);
  const float* p10 = tex + (((size_t)((y1 << 9) | x0) << SH) + co);
  const float* p11 = tex + (((size_t)((y1 << 9) | x1) << SH) + co);
  float4 a = *reinterpret_cast<const float4*>(p00);
  float4 b = *reinterpret_cast<const float4*>(p01);
  float4 c = *reinterpret_cast<const float4*>(p10);
  float4 d = *reinterpret_cast<const float4*>(p11);
  float gx = 1.0f - fx, gy = 1.0f - fy;
  float w00 = gx * gy, w01 = fx * gy, w10 = gx * fy, w11 = fx * fy;
  float4 o;
  o.x = fmaf(d.x, w11, fmaf(c.x, w10, fmaf(b.x, w01, a.x * w00)));
  o.y = fmaf(d.y, w11, fmaf(c.y, w10, fmaf(b.y, w01, a.y * w00)));
  o.z = fmaf(d.z, w11, fmaf(c.z, w10, fmaf(b.z, w01, a.z * w00)));
  o.w = fmaf(d.w, w11, fmaf(c.w, w10, fmaf(b.w, w01, a.w * w00)));
  return o;
}

// Build interleaved texture: ws[texel][0:8]=offset ch, ws[texel][8:16]=rgb ch.
__global__ void __launch_bounds__(256) tex_interleave(
    const float* __restrict__ t0, const float* __restrict__ t1,
    float* __restrict__ ws) {
  int i = blockIdx.x * 256 + threadIdx.x;  // one float4 slot each; 1M slots
  int texel = i >> 2;
  int q = i & 3;
  const float* src = (q < 2 ? t0 : t1) + (((size_t)texel << 3) + ((q & 1) << 2));
  reinterpret_cast<float4*>(ws)[i] = *reinterpret_cast<const float4*>(src);
}

// Pre-pack all MFMA A-fragments (bf16) into a 12 KiB blob.
// Layout: slot = (h*32+m)*12 + F, F in {o1,o2a,o2b,o3a,o3b,r1,r2a,r2b,r3a,r3b,r4a,r4b}.
__global__ void __launch_bounds__(256) pack_weights(
    const float* __restrict__ ow0, const float* __restrict__ ow1,
    const float* __restrict__ ow2, const float* __restrict__ rw0,
    const float* __restrict__ rw1, const float* __restrict__ rw2,
    const float* __restrict__ rw3, u32x4* __restrict__ Wb) {
  for (int slot = threadIdx.x; slot < 768; slot += 256) {
    int F = slot % 12;
    int lb = slot / 12;
    int h = lb >> 5, m = lb & 31;
    u32x4 v = {0u, 0u, 0u, 0u};
    switch (F) {
      case 0:
        if (h == 0) v = pack8(ow0 + 10 * m);
        else { const float* p = ow0 + 10 * m + 8; v = u32x4{pkbf(p[0], p[1]), 0u, 0u, 0u}; }
        break;
      case 1: v = pack8(ow1 + 32 * m + 8 * h); break;
      case 2: v = pack8(ow1 + 32 * m + 16 + 8 * h); break;
      case 3: v = pack8(ow2 + 32 * m + 8 * h); break;
      case 4: v = pack8(ow2 + 32 * m + 16 + 8 * h); break;
      case 5:
        if (h == 0) v = pack8(rw0 + 12 * m);
        else { const float* p = rw0 + 12 * m + 8; v = u32x4{pkbf(p[0], p[1]), pkbf(p[2], p[3]), 0u, 0u}; }
        break;
      case 6: v = pack8(rw1 + 32 * m + 8 * h); break;
      case 7: v = pack8(rw1 + 32 * m + 16 + 8 * h); break;
      case 8: v = pack8(rw2 + 32 * m + 8 * h); break;
      case 9: v = pack8(rw2 + 32 * m + 16 + 8 * h); break;
      case 10: if (m < 3) v = pack8(rw3 + 32 * m + 8 * h); break;
      case 11: if (m < 3) v = pack8(rw3 + 32 * m + 16 + 8 * h); break;
    }
    Wb[slot] = v;
  }
}

// ILV=true: wtex is the 16-ch interleaved texture AND Wb holds prepacked frags.
// ILV=false: fully self-contained fallback (raw textures, in-kernel packing).
// NOTE: no waves-per-EU arg — empirically VGPR_Count = 256/N on this body
// (rounds 5/6/8: N=5,4,3 -> 48,64,84) and live demand ~150+32 AGPR, so any
// cap forces scratch spill (~50-280 MB of HBM RMW). Let the RA allocate.
template <bool ILV>
__global__ void __launch_bounds__(256) neumip_mfma(
    const float* __restrict__ cam_g, const float* __restrict__ light_g,
    const float* __restrict__ uv_g, const float* __restrict__ offset_tex,
    const float* __restrict__ rgb_tex, const float* __restrict__ wtex,
    const u32x4* __restrict__ Wb,
    const float* __restrict__ ow0, const float* __restrict__ ob0,
    const float* __restrict__ ow1, const float* __restrict__ ob1,
    const float* __restrict__ ow2, const float* __restrict__ ob2,
    const float* __restrict__ ow3, const float* __restrict__ ob3,
    const float* __restrict__ rw0, const float* __restrict__ rb0,
    const float* __restrict__ rw1, const float* __restrict__ rb1,
    const float* __restrict__ rw2, const float* __restrict__ rb2,
    const float* __restrict__ rw3, const float* __restrict__ rb3,
    float* __restrict__ out) {
  const int tid = threadIdx.x;
  const int lane = tid & 63;
  const int widx = tid >> 6;
  const int h = lane >> 5;
  const int sl = lane & 31;
  const int m = sl;
  const float* texO = ILV ? wtex : offset_tex;
  const float* texR = ILV ? wtex : rgb_tex;

  // Shuffle-based output redistribution constants.
  const int s1 = lane / 3, c1 = lane - 3 * s1;  // for og[lane]
  const int j2 = 64 + sl;
  const int s2 = j2 / 3, c2 = j2 - 3 * s2;      // for og[64+sl]

  // ---------------- weight fragments ----------------
  const u32x4* Wl = Wb + (h * 32 + m) * 12;
  u32x4 A_o1, A_o2a, A_o2b, A_o3a, A_o3b, A_r1, A_r2a, A_r2b, A_r3a, A_r3b,
      A_r4a, A_r4b;
  if (ILV) {
    A_o1 = Wl[0];  A_o2a = Wl[1]; A_o2b = Wl[2]; A_o3a = Wl[3]; A_o3b = Wl[4];
    A_r1 = Wl[5];  A_r2a = Wl[6]; A_r2b = Wl[7]; A_r3a = Wl[8]; A_r3b = Wl[9];
    A_r4a = Wl[10]; A_r4b = Wl[11];
  } else {
    if (h == 0) {
      A_o1 = pack8(ow0 + 10 * m);
    } else {
      const float* p = ow0 + 10 * m + 8;
      A_o1 = u32x4{pkbf(p[0], p[1]), 0u, 0u, 0u};
    }
    A_o2a = pack8(ow1 + 32 * m + 8 * h);
    A_o2b = pack8(ow1 + 32 * m + 16 + 8 * h);
    A_o3a = pack8(ow2 + 32 * m + 8 * h);
    A_o3b = pack8(ow2 + 32 * m + 16 + 8 * h);
    if (h == 0) {
      A_r1 = pack8(rw0 + 12 * m);
    } else {
      const float* p = rw0 + 12 * m + 8;
      A_r1 = u32x4{pkbf(p[0], p[1]), pkbf(p[2], p[3]), 0u, 0u};
    }
    A_r2a = pack8(rw1 + 32 * m + 8 * h);
    A_r2b = pack8(rw1 + 32 * m + 16 + 8 * h);
    A_r3a = pack8(rw2 + 32 * m + 8 * h);
    A_r3b = pack8(rw2 + 32 * m + 16 + 8 * h);
    if (m < 3) {
      A_r4a = pack8(rw3 + 32 * m + 8 * h);
      A_r4b = pack8(rw3 + 32 * m + 16 + 8 * h);
    } else {
      A_r4a = u32x4{0u, 0u, 0u, 0u};
      A_r4b = u32x4{0u, 0u, 0u, 0u};
    }
  }

  f32x16 w3f;
#pragma unroll
  for (int b = 0; b < 4; ++b) {
    float4 t = *reinterpret_cast<const float4*>(ow3 + 8 * b + 4 * h);
    w3f[4 * b + 0] = t.x; w3f[4 * b + 1] = t.y;
    w3f[4 * b + 2] = t.z; w3f[4 * b + 3] = t.w;
  }
  const float b30 = rb3[0], b31 = rb3[1], b32 = rb3[2];
  const float ob3s = ob3[0];

  // ---------------- grid-stride over 32-sample groups ----------------
  const int NG = BATCH / 32;
  const int nw = (int)(gridDim.x * (blockDim.x >> 6));
  int g = (int)blockIdx.x * (int)(blockDim.x >> 6) + widx;
#pragma unroll 1
  for (; g < NG; g += nw) {
    const int S = g * 32 + sl;
    float2 uvv = reinterpret_cast<const float2*>(uv_g)[S];
    float2 cam = reinterpret_cast<const float2*>(cam_g)[S];
    float2 light = reinterpret_cast<const float2*>(light_g)[S];

    // ---- offset-branch input B-frag ----
    float4 ch = bilin4<ILV>(texO, uvv.x, uvv.y, h, 0);
    unsigned V0 = pkbf(ch.x, ch.y), V1 = pkbf(ch.z, ch.w);
    auto t0 = __builtin_amdgcn_permlane32_swap(V0, V0, false, false);
    auto t1 = __builtin_amdgcn_permlane32_swap(V1, V1, false, false);
    unsigned camk = pkbf(cam.x, cam.y);
    u32x4 Bin;
    Bin[0] = h ? camk : V0;
    Bin[1] = h ? 0u : V1;
    Bin[2] = h ? 0u : t0[1];
    Bin[3] = h ? 0u : t1[1];

    // ---- offset MLP ----
    f32x16 acc = load_bias(ob0, h);
    acc = mfma_bf16(A_o1, Bin, acc);
    u32x4 B0, B1;
    act_pack_swap(acc, B0, B1);
    acc = load_bias(ob1, h);
    acc = mfma_bf16(A_o2a, B0, acc);
    acc = mfma_bf16(A_o2b, B1, acc);
    act_pack_swap(acc, B0, B1);
    acc = load_bias(ob2, h);
    acc = mfma_bf16(A_o3a, B0, acc);
    acc = mfma_bf16(A_o3b, B1, acc);

    float part = 0.0f;
#pragma unroll
    for (int i = 0; i < 16; ++i) {
      float t = acc[i];
      t = fmaxf(t, 0.01f * t);
      part = fmaf(w3f[i], t, part);
    }
    float depth = part + __shfl_xor(part, 32) + ob3s;

    // ---- displacement ----
    float s2f = fmaf(cam.x, cam.x, cam.y * cam.y);
    float z = sqrtf(fmaxf(1.0f - s2f, 1e-6f));
    float drz = depth * (1.0f / z);
    float u2x = fmaf(cam.x, drz, uvv.x);
    float u2y = fmaf(cam.y, drz, uvv.y);

    // ---- rgb-branch input B-frag ----
    float4 chr = bilin4<ILV>(texR, u2x, u2y, h, 1);
    unsigned P0 = pkbf(chr.x, chr.y), P1 = pkbf(chr.z, chr.w);
    u32x4 Brin;
    Brin[0] = h ? P0 : pkbf(light.x, light.y);
    Brin[1] = h ? P1 : camk;
    Brin[2] = h ? 0u : P0;
    Brin[3] = h ? 0u : P1;

    // ---- rgb MLP ----
    acc = load_bias(rb0, h);
    acc = mfma_bf16(A_r1, Brin, acc);
    act_pack_swap(acc, B0, B1);
    acc = load_bias(rb1, h);
    acc = mfma_bf16(A_r2a, B0, acc);
    acc = mfma_bf16(A_r2b, B1, acc);
    act_pack_swap(acc, B0, B1);
    acc = load_bias(rb2, h);
    acc = mfma_bf16(A_r3a, B0, acc);
    acc = mfma_bf16(A_r3b, B1, acc);
    act_pack_swap(acc, B0, B1);
    f32x16 accf;
#pragma unroll
    for (int i = 0; i < 16; ++i) accf[i] = 0.0f;
    accf = mfma_bf16(A_r4a, B0, accf);
    accf = mfma_bf16(A_r4b, B1, accf);

    // ---- shuffle-packed coalesced store ----
    float o0 = accf[0] + b30, o1 = accf[1] + b31, o2 = accf[2] + b32;
    float a0 = __shfl(o0, s1), a1 = __shfl(o1, s1), a2 = __shfl(o2, s1);
    float v1 = (c1 == 0) ? a0 : ((c1 == 1) ? a1 : a2);
    float d0 = __shfl(o0, s2), d1 = __shfl(o1, s2), d2 = __shfl(o2, s2);
    float v2 = (c2 == 0) ? d0 : ((c2 == 1) ? d1 : d2);
    float* og = out + (size_t)g * 96;
    og[lane] = v1;
    if (h == 1) og[64 + sl] = v2;
  }
}

extern "C" void kernel_launch(void* const* d_in, const int* in_sizes, int n_in,
                              void* d_out, int out_size, void* d_ws, size_t ws_size,
                              hipStream_t stream) {
  const float* cam = (const float*)d_in[0];
  const float* light = (const float*)d_in[1];
  const float* uv = (const float*)d_in[2];
  const float* offset_tex = (const float*)d_in[3];
  const float* rgb_tex = (const float*)d_in[4];
  const float* ow0 = (const float*)d_in[5];
  const float* ob0 = (const float*)d_in[6];
  const float* ow1 = (const float*)d_in[7];
  const float* ob1 = (const float*)d_in[8];
  const float* ow2 = (const float*)d_in[9];
  const float* ob2 = (const float*)d_in[10];
  const float* ow3 = (const float*)d_in[11];
  const float* ob3 = (const float*)d_in[12];
  const float* rw0 = (const float*)d_in[13];
  const float* rb0 = (const float*)d_in[14];
  const float* rw1 = (const float*)d_in[15];
  const float* rb1 = (const float*)d_in[16];
  const float* rw2 = (const float*)d_in[17];
  const float* rb2 = (const float*)d_in[18];
  const float* rw3 = (const float*)d_in[19];
  const float* rb3 = (const float*)d_in[20];
  float* out = (float*)d_out;
  float* wtex = (float*)d_ws;
  u32x4* Wb = (u32x4*)((char*)d_ws + ILV_BYTES);

  dim3 block(256);
  if (ws_size >= ILV_BYTES + WBLOB_BYTES) {
    hipLaunchKernelGGL(tex_interleave, dim3(4096), block, 0, stream, offset_tex,
                       rgb_tex, wtex);
    hipLaunchKernelGGL(pack_weights, dim3(1), block, 0, stream, ow0, ow1, ow2,
                       rw0, rw1, rw2, rw3, Wb);
    hipLaunchKernelGGL(neumip_mfma<true>, dim3(2048), block, 0, stream, cam,
                       light, uv, offset_tex, rgb_tex, wtex, Wb, ow0, ob0, ow1,
                       ob1, ow2, ob2, ow3, ob3, rw0, rb0, rw1, rb1, rw2, rb2,
                       rw3, rb3, out);
  } else {
    hipLaunchKernelGGL(neumip_mfma<false>, dim3(2048), block, 0, stream, cam,
                       light, uv, offset_tex, rgb_tex, wtex, Wb, ow0, ob0, ow1,
                       ob1, ow2, ob2, ow3, ob3, rw0, rb0, rw1, rb1, rw2, rb2,
                       rw3, rb3, out);
  }
}

// Round 11
// 201.919 us; speedup vs baseline: 1.9810x; 1.0174x over previous
//
#include <hip/hip_runtime.h>
#include <hip/hip_bf16.h>

static constexpr int BATCH = 1 << 20;
static constexpr size_t ILV_BYTES = (size_t)512 * 512 * 16 * 4;  // 16 MiB
static constexpr size_t WBLOB_BYTES = 768 * 16;                  // 12 KiB

using f32x16 = __attribute__((ext_vector_type(16))) float;
using s16x8  = __attribute__((ext_vector_type(8))) short;
using u32x4  = __attribute__((ext_vector_type(4))) unsigned int;

__device__ __forceinline__ unsigned pkbf(float lo, float hi) {
  unsigned short a = __builtin_bit_cast(unsigned short, __float2bfloat16(lo));
  unsigned short b = __builtin_bit_cast(unsigned short, __float2bfloat16(hi));
  return (unsigned)a | ((unsigned)b << 16);
}

__device__ __forceinline__ u32x4 pack8(const float* __restrict__ p) {
  u32x4 r = {pkbf(p[0], p[1]), pkbf(p[2], p[3]), pkbf(p[4], p[5]), pkbf(p[6], p[7])};
  return r;
}

__device__ __forceinline__ f32x16 mfma_bf16(u32x4 a, u32x4 b, f32x16 c) {
  return __builtin_amdgcn_mfma_f32_32x32x16_bf16(
      __builtin_bit_cast(s16x8, a), __builtin_bit_cast(s16x8, b), c, 0, 0, 0);
}

// D(f32x16) -> leaky -> bf16 B-frags for next layer (K=32).
__device__ __forceinline__ void act_pack_swap(f32x16 acc, u32x4& B0, u32x4& B1) {
  float r[16];
#pragma unroll
  for (int i = 0; i < 16; ++i) {
    float t = acc[i];
    r[i] = fmaxf(t, 0.01f * t);
  }
  unsigned pk[4][2];
#pragma unroll
  for (int b = 0; b < 4; ++b) {
    pk[b][0] = pkbf(r[4 * b + 0], r[4 * b + 1]);
    pk[b][1] = pkbf(r[4 * b + 2], r[4 * b + 3]);
  }
  auto r0 = __builtin_amdgcn_permlane32_swap(pk[0][0], pk[1][0], false, false);
  auto r1 = __builtin_amdgcn_permlane32_swap(pk[0][1], pk[1][1], false, false);
  auto r2 = __builtin_amdgcn_permlane32_swap(pk[2][0], pk[3][0], false, false);
  auto r3 = __builtin_amdgcn_permlane32_swap(pk[2][1], pk[3][1], false, false);
  B0[0] = r0[0]; B0[1] = r1[0]; B0[2] = r0[1]; B0[3] = r1[1];
  B1[0] = r2[0]; B1[1] = r3[0]; B1[2] = r2[1]; B1[3] = r3[1];
}

__device__ __forceinline__ f32x16 load_bias(const float* __restrict__ bp, int h) {
  f32x16 c;
#pragma unroll
  for (int b = 0; b < 4; ++b) {
    float4 t = *reinterpret_cast<const float4*>(bp + 8 * b + 4 * h);
    c[4 * b + 0] = t.x; c[4 * b + 1] = t.y; c[4 * b + 2] = t.z; c[4 * b + 3] = t.w;
  }
  return c;
}

// 4 channels (h: ch4h..4h+3) of bilinear-wrap sample. which: 0=offset,1=rgb.
template <bool ILV>
__device__ __forceinline__ float4 bilin4(const float* __restrict__ tex, float ux,
                                         float uy, int h, int which) {
  float px = ux * 512.0f - 0.5f;
  float py = uy * 512.0f - 0.5f;
  float fpx = floorf(px), fpy = floorf(py);
  float fx = px - fpx, fy = py - fpy;
  int ix = (int)fpx, iy = (int)fpy;
  int x0 = ix & 511, x1 = (ix + 1) & 511;
  int y0 = iy & 511, y1 = (iy + 1) & 511;
  constexpr int SH = ILV ? 4 : 3;
  const int co = (ILV ? (which << 3) : 0) + (h << 2);
  const float* p00 = tex + (((size_t)((y0 << 9) | x0) << SH) + co);
  const float* p01 = tex + (((size_t)((y0 << 9) | x1) << SH) + co);
  const float* p10 = tex + (((size_t)((y1 << 9) | x0) << SH) + co);
  const float* p11 = tex + (((size_t)((y1 << 9) | x1) << SH) + co);
  float4 a = *reinterpret_cast<const float4*>(p00);
  float4 b = *reinterpret_cast<const float4*>(p01);
  float4 c = *reinterpret_cast<const float4*>(p10);
  float4 d = *reinterpret_cast<const float4*>(p11);
  float gx = 1.0f - fx, gy = 1.0f - fy;
  float w00 = gx * gy, w01 = fx * gy, w10 = gx * fy, w11 = fx * fy;
  float4 o;
  o.x = fmaf(d.x, w11, fmaf(c.x, w10, fmaf(b.x, w01, a.x * w00)));
  o.y = fmaf(d.y, w11, fmaf(c.y, w10, fmaf(b.y, w01, a.y * w00)));
  o.z = fmaf(d.z, w11, fmaf(c.z, w10, fmaf(b.z, w01, a.z * w00)));
  o.w = fmaf(d.w, w11, fmaf(c.w, w10, fmaf(b.w, w01, a.w * w00)));
  return o;
}

// Build interleaved texture: ws[texel][0:8]=offset ch, ws[texel][8:16]=rgb ch.
__global__ void __launch_bounds__(256) tex_interleave(
    const float* __restrict__ t0, const float* __restrict__ t1,
    float* __restrict__ ws) {
  int i = blockIdx.x * 256 + threadIdx.x;  // one float4 slot each; 1M slots
  int texel = i >> 2;
  int q = i & 3;
  const float* src = (q < 2 ? t0 : t1) + (((size_t)texel << 3) + ((q & 1) << 2));
  reinterpret_cast<float4*>(ws)[i] = *reinterpret_cast<const float4*>(src);
}

// Pre-pack all MFMA A-fragments (bf16) into a 12 KiB blob.
// Layout: slot = (h*32+m)*12 + F, F in {o1,o2a,o2b,o3a,o3b,r1,r2a,r2b,r3a,r3b,r4a,r4b}.
__global__ void __launch_bounds__(256) pack_weights(
    const float* __restrict__ ow0, const float* __restrict__ ow1,
    const float* __restrict__ ow2, const float* __restrict__ rw0,
    const float* __restrict__ rw1, const float* __restrict__ rw2,
    const float* __restrict__ rw3, u32x4* __restrict__ Wb) {
  int slot = blockIdx.x * 256 + threadIdx.x;
  if (slot < 768) {
    int F = slot % 12;
    int lb = slot / 12;
    int h = lb >> 5, m = lb & 31;
    u32x4 v = {0u, 0u, 0u, 0u};
    switch (F) {
      case 0:
        if (h == 0) v = pack8(ow0 + 10 * m);
        else { const float* p = ow0 + 10 * m + 8; v = u32x4{pkbf(p[0], p[1]), 0u, 0u, 0u}; }
        break;
      case 1: v = pack8(ow1 + 32 * m + 8 * h); break;
      case 2: v = pack8(ow1 + 32 * m + 16 + 8 * h); break;
      case 3: v = pack8(ow2 + 32 * m + 8 * h); break;
      case 4: v = pack8(ow2 + 32 * m + 16 + 8 * h); break;
      case 5:
        if (h == 0) v = pack8(rw0 + 12 * m);
        else { const float* p = rw0 + 12 * m + 8; v = u32x4{pkbf(p[0], p[1]), pkbf(p[2], p[3]), 0u, 0u}; }
        break;
      case 6: v = pack8(rw1 + 32 * m + 8 * h); break;
      case 7: v = pack8(rw1 + 32 * m + 16 + 8 * h); break;
      case 8: v = pack8(rw2 + 32 * m + 8 * h); break;
      case 9: v = pack8(rw2 + 32 * m + 16 + 8 * h); break;
      case 10: if (m < 3) v = pack8(rw3 + 32 * m + 8 * h); break;
      case 11: if (m < 3) v = pack8(rw3 + 32 * m + 16 + 8 * h); break;
    }
    Wb[slot] = v;
  }
}

// Software-pipelined main kernel: the offset-texture gather and input loads of
// group g+nw are issued between issue and consumption of group g's rgb gather,
// hiding the offset-gather latency under g's rgb-phase compute.
// No waves-per-EU cap: any cap forces scratch spill (rounds 5-9; VGPR=256/N law).
template <bool ILV>
__global__ void __launch_bounds__(256) neumip_mfma(
    const float* __restrict__ cam_g, const float* __restrict__ light_g,
    const float* __restrict__ uv_g, const float* __restrict__ offset_tex,
    const float* __restrict__ rgb_tex, const float* __restrict__ wtex,
    const u32x4* __restrict__ Wb,
    const float* __restrict__ ow0, const float* __restrict__ ob0,
    const float* __restrict__ ow1, const float* __restrict__ ob1,
    const float* __restrict__ ow2, const float* __restrict__ ob2,
    const float* __restrict__ ow3, const float* __restrict__ ob3,
    const float* __restrict__ rw0, const float* __restrict__ rb0,
    const float* __restrict__ rw1, const float* __restrict__ rb1,
    const float* __restrict__ rw2, const float* __restrict__ rb2,
    const float* __restrict__ rw3, const float* __restrict__ rb3,
    float* __restrict__ out) {
  const int tid = threadIdx.x;
  const int lane = tid & 63;
  const int widx = tid >> 6;
  const int h = lane >> 5;
  const int sl = lane & 31;
  const int m = sl;
  const float* texO = ILV ? wtex : offset_tex;
  const float* texR = ILV ? wtex : rgb_tex;

  // Shuffle-based output redistribution constants.
  const int s1 = lane / 3, c1 = lane - 3 * s1;  // for og[lane]
  const int j2 = 64 + sl;
  const int s2 = j2 / 3, c2 = j2 - 3 * s2;      // for og[64+sl]

  // ---------------- weight fragments ----------------
  const u32x4* Wl = Wb + (h * 32 + m) * 12;
  u32x4 A_o1, A_o2a, A_o2b, A_o3a, A_o3b, A_r1, A_r2a, A_r2b, A_r3a, A_r3b,
      A_r4a, A_r4b;
  if (ILV) {
    A_o1 = Wl[0];  A_o2a = Wl[1]; A_o2b = Wl[2]; A_o3a = Wl[3]; A_o3b = Wl[4];
    A_r1 = Wl[5];  A_r2a = Wl[6]; A_r2b = Wl[7]; A_r3a = Wl[8]; A_r3b = Wl[9];
    A_r4a = Wl[10]; A_r4b = Wl[11];
  } else {
    if (h == 0) {
      A_o1 = pack8(ow0 + 10 * m);
    } else {
      const float* p = ow0 + 10 * m + 8;
      A_o1 = u32x4{pkbf(p[0], p[1]), 0u, 0u, 0u};
    }
    A_o2a = pack8(ow1 + 32 * m + 8 * h);
    A_o2b = pack8(ow1 + 32 * m + 16 + 8 * h);
    A_o3a = pack8(ow2 + 32 * m + 8 * h);
    A_o3b = pack8(ow2 + 32 * m + 16 + 8 * h);
    if (h == 0) {
      A_r1 = pack8(rw0 + 12 * m);
    } else {
      const float* p = rw0 + 12 * m + 8;
      A_r1 = u32x4{pkbf(p[0], p[1]), pkbf(p[2], p[3]), 0u, 0u};
    }
    A_r2a = pack8(rw1 + 32 * m + 8 * h);
    A_r2b = pack8(rw1 + 32 * m + 16 + 8 * h);
    A_r3a = pack8(rw2 + 32 * m + 8 * h);
    A_r3b = pack8(rw2 + 32 * m + 16 + 8 * h);
    if (m < 3) {
      A_r4a = pack8(rw3 + 32 * m + 8 * h);
      A_r4b = pack8(rw3 + 32 * m + 16 + 8 * h);
    } else {
      A_r4a = u32x4{0u, 0u, 0u, 0u};
      A_r4b = u32x4{0u, 0u, 0u, 0u};
    }
  }

  f32x16 w3f;
#pragma unroll
  for (int b = 0; b < 4; ++b) {
    float4 t = *reinterpret_cast<const float4*>(ow3 + 8 * b + 4 * h);
    w3f[4 * b + 0] = t.x; w3f[4 * b + 1] = t.y;
    w3f[4 * b + 2] = t.z; w3f[4 * b + 3] = t.w;
  }
  const float b30 = rb3[0], b31 = rb3[1], b32 = rb3[2];
  const float ob3s = ob3[0];

  const float2* uv2g = reinterpret_cast<const float2*>(uv_g);
  const float2* cam2g = reinterpret_cast<const float2*>(cam_g);
  const float2* light2g = reinterpret_cast<const float2*>(light_g);

  // ---------------- pipelined grid-stride over 32-sample groups ----------------
  const int NG = BATCH / 32;
  const int nw = (int)(gridDim.x * (blockDim.x >> 6));
  int g = (int)blockIdx.x * (int)(blockDim.x >> 6) + widx;
  if (g >= NG) return;

  // prologue: stage inputs + offset gather for first group
  float2 uvv = uv2g[g * 32 + sl];
  float2 cam = cam2g[g * 32 + sl];
  float2 light = light2g[g * 32 + sl];
  float4 ch = bilin4<ILV>(texO, uvv.x, uvv.y, h, 0);

#pragma unroll 1
  for (; g < NG; g += nw) {
    // prefetch next group's inputs (clamped tail re-reads current group)
    const int gn = (g + nw < NG) ? g + nw : g;
    const int Sn = gn * 32 + sl;
    float2 uvn = uv2g[Sn];
    float2 camn = cam2g[Sn];
    float2 lightn = light2g[Sn];

    // ---- offset-branch input B-frag (from prefetched ch) ----
    unsigned V0 = pkbf(ch.x, ch.y), V1 = pkbf(ch.z, ch.w);
    auto t0 = __builtin_amdgcn_permlane32_swap(V0, V0, false, false);
    auto t1 = __builtin_amdgcn_permlane32_swap(V1, V1, false, false);
    unsigned camk = pkbf(cam.x, cam.y);
    u32x4 Bin;
    Bin[0] = h ? camk : V0;
    Bin[1] = h ? 0u : V1;
    Bin[2] = h ? 0u : t0[1];
    Bin[3] = h ? 0u : t1[1];

    // ---- offset MLP ----
    f32x16 acc = load_bias(ob0, h);
    acc = mfma_bf16(A_o1, Bin, acc);
    u32x4 B0, B1;
    act_pack_swap(acc, B0, B1);
    acc = load_bias(ob1, h);
    acc = mfma_bf16(A_o2a, B0, acc);
    acc = mfma_bf16(A_o2b, B1, acc);
    act_pack_swap(acc, B0, B1);
    acc = load_bias(ob2, h);
    acc = mfma_bf16(A_o3a, B0, acc);
    acc = mfma_bf16(A_o3b, B1, acc);

    float part = 0.0f;
#pragma unroll
    for (int i = 0; i < 16; ++i) {
      float t = acc[i];
      t = fmaxf(t, 0.01f * t);
      part = fmaf(w3f[i], t, part);
    }
    float depth = part + __shfl_xor(part, 32) + ob3s;

    // ---- displacement ----
    float s2f = fmaf(cam.x, cam.x, cam.y * cam.y);
    float z = sqrtf(fmaxf(1.0f - s2f, 1e-6f));
    float drz = depth * (1.0f / z);
    float u2x = fmaf(cam.x, drz, uvv.x);
    float u2y = fmaf(cam.y, drz, uvv.y);

    // ---- issue rgb gather (g), then next offset gather (g+nw) ----
    // chr is consumed below; chn stays in flight across the rgb MLP.
    float4 chr = bilin4<ILV>(texR, u2x, u2y, h, 1);
    float4 chn = bilin4<ILV>(texO, uvn.x, uvn.y, h, 0);

    // ---- rgb-branch input B-frag ----
    unsigned P0 = pkbf(chr.x, chr.y), P1 = pkbf(chr.z, chr.w);
    u32x4 Brin;
    Brin[0] = h ? P0 : pkbf(light.x, light.y);
    Brin[1] = h ? P1 : camk;
    Brin[2] = h ? 0u : P0;
    Brin[3] = h ? 0u : P1;

    // ---- rgb MLP ----
    acc = load_bias(rb0, h);
    acc = mfma_bf16(A_r1, Brin, acc);
    act_pack_swap(acc, B0, B1);
    acc = load_bias(rb1, h);
    acc = mfma_bf16(A_r2a, B0, acc);
    acc = mfma_bf16(A_r2b, B1, acc);
    act_pack_swap(acc, B0, B1);
    acc = load_bias(rb2, h);
    acc = mfma_bf16(A_r3a, B0, acc);
    acc = mfma_bf16(A_r3b, B1, acc);
    act_pack_swap(acc, B0, B1);
    f32x16 accf;
#pragma unroll
    for (int i = 0; i < 16; ++i) accf[i] = 0.0f;
    accf = mfma_bf16(A_r4a, B0, accf);
    accf = mfma_bf16(A_r4b, B1, accf);

    // ---- shuffle-packed coalesced store ----
    float o0 = accf[0] + b30, o1 = accf[1] + b31, o2 = accf[2] + b32;
    float a0 = __shfl(o0, s1), a1 = __shfl(o1, s1), a2 = __shfl(o2, s1);
    float v1 = (c1 == 0) ? a0 : ((c1 == 1) ? a1 : a2);
    float d0 = __shfl(o0, s2), d1 = __shfl(o1, s2), d2 = __shfl(o2, s2);
    float v2 = (c2 == 0) ? d0 : ((c2 == 1) ? d1 : d2);
    float* og = out + (size_t)g * 96;
    og[lane] = v1;
    if (h == 1) og[64 + sl] = v2;

    // rotate pipeline registers
    uvv = uvn; cam = camn; light = lightn; ch = chn;
  }
}

extern "C" void kernel_launch(void* const* d_in, const int* in_sizes, int n_in,
                              void* d_out, int out_size, void* d_ws, size_t ws_size,
                              hipStream_t stream) {
  const float* cam = (const float*)d_in[0];
  const float* light = (const float*)d_in[1];
  const float* uv = (const float*)d_in[2];
  const float* offset_tex = (const float*)d_in[3];
  const float* rgb_tex = (const float*)d_in[4];
  const float* ow0 = (const float*)d_in[5];
  const float* ob0 = (const float*)d_in[6];
  const float* ow1 = (const float*)d_in[7];
  const float* ob1 = (const float*)d_in[8];
  const float* ow2 = (const float*)d_in[9];
  const float* ob2 = (const float*)d_in[10];
  const float* ow3 = (const float*)d_in[11];
  const float* ob3 = (const float*)d_in[12];
  const float* rw0 = (const float*)d_in[13];
  const float* rb0 = (const float*)d_in[14];
  const float* rw1 = (const float*)d_in[15];
  const float* rb1 = (const float*)d_in[16];
  const float* rw2 = (const float*)d_in[17];
  const float* rb2 = (const float*)d_in[18];
  const float* rw3 = (const float*)d_in[19];
  const float* rb3 = (const float*)d_in[20];
  float* out = (float*)d_out;
  float* wtex = (float*)d_ws;
  u32x4* Wb = (u32x4*)((char*)d_ws + ILV_BYTES);

  dim3 block(256);
  if (ws_size >= ILV_BYTES + WBLOB_BYTES) {
    hipLaunchKernelGGL(tex_interleave, dim3(4096), block, 0, stream, offset_tex,
                       rgb_tex, wtex);
    hipLaunchKernelGGL(pack_weights, dim3(3), block, 0, stream, ow0, ow1, ow2,
                       rw0, rw1, rw2, rw3, Wb);
    hipLaunchKernelGGL(neumip_mfma<true>, dim3(2048), block, 0, stream, cam,
                       light, uv, offset_tex, rgb_tex, wtex, Wb, ow0, ob0, ow1,
                       ob1, ow2, ob2, ow3, ob3, rw0, rb0, rw1, rb1, rw2, rb2,
                       rw3, rb3, out);
  } else {
    hipLaunchKernelGGL(neumip_mfma<false>, dim3(2048), block, 0, stream, cam,
                       light, uv, offset_tex, rgb_tex, wtex, Wb, ow0, ob0, ow1,
                       ob1, ow2, ob2, ow3, ob3, rw0, rb0, rw1, rb1, rw2, rb2,
                       rw3, rb3, out);
  }
}